// Round 2
// baseline (284.905 us; speedup 1.0000x reference)
//
#include <hip/hip_runtime.h>
#include <hip/hip_bf16.h>
#include <hip/hip_fp16.h>

using bf16 = __hip_bfloat16;
typedef __attribute__((ext_vector_type(8))) short short8;
typedef __attribute__((ext_vector_type(4))) float f32x4;

static constexpr int Bb = 2, Ss = 1024, Dd = 1024, Ee = 64, Nn = 16;

__device__ __forceinline__ unsigned short f2bfr(float f) {
    __hip_bfloat16 h = __float2bfloat16(f);
    return *reinterpret_cast<unsigned short*>(&h);
}

// ---------------- f32 -> bf16 elementwise cast (X) ----------------
__global__ __launch_bounds__(256) void k_cast(
    const float* __restrict__ in, bf16* __restrict__ out)
{
    int i = blockIdx.x * 256 + threadIdx.x;
    float4 v = ((const float4*)in)[i];
    ushort4 y;
    y.x = f2bfr(v.x); y.y = f2bfr(v.y); y.z = f2bfr(v.z); y.w = f2bfr(v.w);
    ((ushort4*)out)[i] = y;
}

// ---------------- f32 transpose+cast: out_bf16[c][r] = in_f32[r][c] ----------------
__global__ __launch_bounds__(256) void k_transpose_f2b(
    const float* __restrict__ in, bf16* __restrict__ out, int R, int C)
{
    __shared__ float tile[64][65];
    int tx = threadIdx.x & 63, ty = threadIdx.x >> 6;
    int r0 = blockIdx.y * 64, c0 = blockIdx.x * 64;
    #pragma unroll
    for (int i = 0; i < 16; ++i)
        tile[ty + i*4][tx] = in[(long)(r0 + ty + i*4)*C + c0 + tx];
    __syncthreads();
    #pragma unroll
    for (int i = 0; i < 16; ++i)
        out[(long)(c0 + ty + i*4)*R + r0 + tx] = __float2bfloat16(tile[tx][ty + i*4]);
}

// ---------------- bf16 transpose: out[c][r] = in[r][c] ----------------
__global__ __launch_bounds__(256) void k_transpose_bf(
    const bf16* __restrict__ in, bf16* __restrict__ out,
    int R, int C, long sIn, long sOut)
{
    in  += (long)blockIdx.z * sIn;
    out += (long)blockIdx.z * sOut;
    __shared__ bf16 tile[64][65];
    int tx = threadIdx.x & 63, ty = threadIdx.x >> 6;
    int r0 = blockIdx.y * 64, c0 = blockIdx.x * 64;
    #pragma unroll
    for (int i = 0; i < 16; ++i)
        tile[ty + i*4][tx] = in[(long)(r0 + ty + i*4)*C + c0 + tx];
    __syncthreads();
    #pragma unroll
    for (int i = 0; i < 16; ++i)
        out[(long)(c0 + ty + i*4)*R + r0 + tx] = tile[tx][ty + i*4];
}

// ---------------- positions + splat influence -> w[b*S+s][16] f32 ----------------
__global__ __launch_bounds__(256) void k_pos_influence(
    const float* __restrict__ X, const float* __restrict__ Wp,
    const float* __restrict__ pb, const float* __restrict__ pbias,
    const float* __restrict__ spos, const float* __restrict__ lsc,
    float* __restrict__ wout)
{
    __shared__ float xl[4*1024];
    __shared__ float part[4][4][64];
    __shared__ float P[4][65];
    __shared__ float sp[16][65];
    int tid = threadIdx.x;
    long g0 = (long)blockIdx.x * 4;     // first of 4 token rows
    const float4* Xg = (const float4*)(X + g0*Dd);
    #pragma unroll
    for (int i = 0; i < 4; ++i)
        ((float4*)xl)[tid + i*256] = Xg[tid + i*256];
    for (int idx = tid; idx < 16*64; idx += 256)
        sp[idx >> 6][idx & 63] = spos[idx];
    __syncthreads();

    int e = tid & 63, ds = tid >> 6;    // ds = K-split index
    float a0 = 0.f, a1 = 0.f, a2 = 0.f, a3 = 0.f;
    int dBase = ds * 256;
    #pragma unroll 8
    for (int d = 0; d < 256; ++d) {
        float wv = Wp[(dBase + d)*Ee + e];
        a0 += wv * xl[0*1024 + dBase + d];
        a1 += wv * xl[1*1024 + dBase + d];
        a2 += wv * xl[2*1024 + dBase + d];
        a3 += wv * xl[3*1024 + dBase + d];
    }
    part[ds][0][e] = a0; part[ds][1][e] = a1; part[ds][2][e] = a2; part[ds][3][e] = a3;
    __syncthreads();
    int r = ds;
    float acc = part[0][r][e] + part[1][r][e] + part[2][r][e] + part[3][r][e];
    int srow = (int)((g0 + r) & (Ss - 1));
    float p = tanhf(acc + pb[e]) + pbias[srow*Ee + e];
    P[r][e] = p;
    __syncthreads();
    if (tid < 64) {
        int rr = tid >> 4, n = tid & 15;
        float d2 = 0.f;
        #pragma unroll 8
        for (int ee = 0; ee < 64; ++ee) { float df = P[rr][ee] - sp[n][ee]; d2 += df*df; }
        float sc = __expf(lsc[n]);
        sc = fminf(fmaxf(sc, 0.3f), 2.0f);
        float infl = fmaxf(__expf(-0.5f * d2 / (sc*sc)), 0.01f);
        wout[(g0 + rr)*Nn + n] = infl;
    }
}

// ---------------- C = scale * A @ Bt^T  (bf16 in, K-contiguous) ----------------
// causal=1: skip tiles with n0 > m0. causal=2: K-loop bound m0+128 (A lower-tri).
template<int OUT_BF16>
__global__ __launch_bounds__(256) void k_gemm_bt(
    const bf16* __restrict__ A, const bf16* __restrict__ Bt, void* __restrict__ Cv,
    int M, int N, int K, long sA, long sB, long sC, float scale, int causal)
{
    int z = blockIdx.z;
    const bf16* Ab = A  + (long)z * sA;
    const bf16* Bw = Bt + (long)z * sB;
    int bm = blockIdx.y, bn = blockIdx.x;
    if (causal == 1 && bn > bm) return;
    int m0 = bm * 128, n0 = bn * 128;
    int kEnd = (causal == 2) ? ((m0 + 128 < K) ? m0 + 128 : K) : K;

    __shared__ short lA[128*32];
    __shared__ short lB[128*32];
    int tid = threadIdx.x, wid = tid >> 6, lane = tid & 63;
    int wm = (wid >> 1)*64, wn = (wid & 1)*64;
    int r16 = lane & 15, quad = lane >> 4;

    f32x4 acc[4][4];
    #pragma unroll
    for (int i = 0; i < 4; ++i)
        #pragma unroll
        for (int j = 0; j < 4; ++j)
            #pragma unroll
            for (int c = 0; c < 4; ++c) acc[i][j][c] = 0.f;

    // staging: 512 16B-chunks per tile; chunk c -> row=c>>2, k-offset=(c&3)*8
    int c0 = wid*64 + lane, c1 = c0 + 256;
    int ra0 = c0 >> 2, ka0 = (c0 & 3)*8;
    int ra1 = c1 >> 2, ka1 = (c1 & 3)*8;
    const short* Ag = (const short*)Ab;
    const short* Bg = (const short*)Bw;

    for (int k0 = 0; k0 < kEnd; k0 += 32) {
        __syncthreads();
        __builtin_amdgcn_global_load_lds(
            (const __attribute__((address_space(1))) void*)(Ag + (long)(m0+ra0)*K + k0 + ka0),
            (__attribute__((address_space(3))) void*)(lA + c0*8), 16, 0, 0);
        __builtin_amdgcn_global_load_lds(
            (const __attribute__((address_space(1))) void*)(Ag + (long)(m0+ra1)*K + k0 + ka1),
            (__attribute__((address_space(3))) void*)(lA + c1*8), 16, 0, 0);
        __builtin_amdgcn_global_load_lds(
            (const __attribute__((address_space(1))) void*)(Bg + (long)(n0+ra0)*K + k0 + ka0),
            (__attribute__((address_space(3))) void*)(lB + c0*8), 16, 0, 0);
        __builtin_amdgcn_global_load_lds(
            (const __attribute__((address_space(1))) void*)(Bg + (long)(n0+ra1)*K + k0 + ka1),
            (__attribute__((address_space(3))) void*)(lB + c1*8), 16, 0, 0);
        __syncthreads();

        short8 af[4], bfv[4];
        #pragma unroll
        for (int i = 0; i < 4; ++i) af[i]  = *(const short8*)(lA + (wm + i*16 + r16)*32 + quad*8);
        #pragma unroll
        for (int j = 0; j < 4; ++j) bfv[j] = *(const short8*)(lB + (wn + j*16 + r16)*32 + quad*8);
        #pragma unroll
        for (int i = 0; i < 4; ++i)
            #pragma unroll
            for (int j = 0; j < 4; ++j)
                acc[i][j] = __builtin_amdgcn_mfma_f32_16x16x32_bf16(af[i], bfv[j], acc[i][j], 0, 0, 0);
    }

    if (OUT_BF16) {
        bf16* C = (bf16*)Cv + (long)z * sC;
        #pragma unroll
        for (int i = 0; i < 4; ++i)
            #pragma unroll
            for (int j = 0; j < 4; ++j)
                #pragma unroll
                for (int rr = 0; rr < 4; ++rr) {
                    long row = m0 + wm + i*16 + quad*4 + rr;
                    long col = n0 + wn + j*16 + r16;
                    C[row*N + col] = __float2bfloat16(acc[i][j][rr] * scale);
                }
    } else {
        float* C = (float*)Cv + (long)z * sC;
        #pragma unroll
        for (int i = 0; i < 4; ++i)
            #pragma unroll
            for (int j = 0; j < 4; ++j)
                #pragma unroll
                for (int rr = 0; rr < 4; ++rr) {
                    long row = m0 + wm + i*16 + quad*4 + rr;
                    long col = n0 + wn + j*16 + r16;
                    C[row*N + col] = acc[i][j][rr] * scale;
                }
    }
}

// ---------------- block reduce helpers (16 lanes-worth of scalars) ----------------
__device__ __forceinline__ void reduce16_max(float* v, float (*red)[16], int wid, int lane) {
    #pragma unroll
    for (int n = 0; n < 16; ++n)
        #pragma unroll
        for (int off = 32; off > 0; off >>= 1)
            v[n] = fmaxf(v[n], __shfl_xor(v[n], off));
    if (lane == 0) {
        #pragma unroll
        for (int n = 0; n < 16; ++n) red[wid][n] = v[n];
    }
    __syncthreads();
    #pragma unroll
    for (int n = 0; n < 16; ++n)
        v[n] = fmaxf(fmaxf(red[0][n], red[1][n]), fmaxf(red[2][n], red[3][n]));
}
__device__ __forceinline__ void reduce16_sum(float* v, float (*red)[16], int wid, int lane) {
    #pragma unroll
    for (int n = 0; n < 16; ++n)
        #pragma unroll
        for (int off = 32; off > 0; off >>= 1)
            v[n] += __shfl_xor(v[n], off);
    if (lane == 0) {
        #pragma unroll
        for (int n = 0; n < 16; ++n) red[wid][n] = v[n];
    }
    __syncthreads();
    #pragma unroll
    for (int n = 0; n < 16; ++n)
        v[n] = red[0][n] + red[1][n] + red[2][n] + red[3][n];
}

// ---------------- per-row: 16-splat softmax + gated average -> A_avg (bf16) ----------------
__global__ __launch_bounds__(256) void k_softmax_avg(
    const float* __restrict__ qk, const float* __restrict__ w,
    const float* __restrict__ gates, bf16* __restrict__ Aout)
{
    int i = blockIdx.x, b = blockIdx.y;
    const float* qrow = qk + ((long)b*Ss + i)*Ss;
    const float* wb   = w  + (long)b*Ss*Nn;
    bf16* arow        = Aout + ((long)b*Ss + i)*Ss;

    __shared__ __half2 wt[1024][9];   // padded stride to break bank conflicts
    __shared__ float wiS[16];
    __shared__ float redA[4][16];
    __shared__ float redB[4][16];

    int tid = threadIdx.x, wid = tid >> 6, lane = tid & 63;

    for (int j = tid; j <= i; j += 256) {
        const float* src = wb + j*16;
        #pragma unroll
        for (int h = 0; h < 8; ++h)
            wt[j][h] = __float22half2_rn(make_float2(src[2*h], src[2*h + 1]));
    }
    if (tid < 16) wiS[tid] = wb[(long)i*16 + tid];
    __syncthreads();

    float wiR[16], m[16], l[16];
    #pragma unroll
    for (int n = 0; n < 16; ++n) { wiR[n] = wiS[n]; m[n] = -1e30f; l[n] = 0.f; }

    // pass 1: row max per splat
    for (int j = tid; j <= i; j += 256) {
        float q = qrow[j];
        #pragma unroll
        for (int h = 0; h < 8; ++h) {
            float2 f = __half22float2(wt[j][h]);
            m[2*h]     = fmaxf(m[2*h],     wiR[2*h]     * f.x * q);
            m[2*h + 1] = fmaxf(m[2*h + 1], wiR[2*h + 1] * f.y * q);
        }
    }
    reduce16_max(m, redA, wid, lane);

    // pass 2: denominators
    for (int j = tid; j <= i; j += 256) {
        float q = qrow[j];
        #pragma unroll
        for (int h = 0; h < 8; ++h) {
            float2 f = __half22float2(wt[j][h]);
            l[2*h]     += __expf(wiR[2*h]     * f.x * q - m[2*h]);
            l[2*h + 1] += __expf(wiR[2*h + 1] * f.y * q - m[2*h + 1]);
        }
    }
    reduce16_sum(l, redB, wid, lane);

    float coef[16];
    #pragma unroll
    for (int n = 0; n < 16; ++n) {
        float g  = gates[n];
        float sg = 1.f / (1.f + __expf(-g));
        coef[n]  = sg / (16.f * l[n]);
    }

    // pass 3: averaged attention row (zero beyond diagonal)
    for (int j = tid; j < Ss; j += 256) {
        float a = 0.f;
        if (j <= i) {
            float q = qrow[j];
            #pragma unroll
            for (int h = 0; h < 8; ++h) {
                float2 f = __half22float2(wt[j][h]);
                a += coef[2*h]     * __expf(wiR[2*h]     * f.x * q - m[2*h]);
                a += coef[2*h + 1] * __expf(wiR[2*h + 1] * f.y * q - m[2*h + 1]);
            }
        }
        arow[j] = __float2bfloat16(a);
    }
}

// ---------------- residual + LayerNorm epilogue (all f32) ----------------
__global__ __launch_bounds__(256) void k_epilogue(
    const float* __restrict__ comb, const float* __restrict__ X,
    const float* __restrict__ lnw, const float* __restrict__ lnb,
    const float* __restrict__ rwp, float* __restrict__ out)
{
    long row = blockIdx.x;
    int tid = threadIdx.x, wid = tid >> 6, lane = tid & 63;
    float rw = 1.f / (1.f + __expf(-rwp[0]));
    float4 cv = ((const float4*)(comb + row*Dd))[tid];
    float4 xv = ((const float4*)(X + row*Dd))[tid];
    float o[4];
    o[0] = rw * xv.x + (1.f - rw) * cv.x;
    o[1] = rw * xv.y + (1.f - rw) * cv.y;
    o[2] = rw * xv.z + (1.f - rw) * cv.z;
    o[3] = rw * xv.w + (1.f - rw) * cv.w;
    float s = o[0] + o[1] + o[2] + o[3];
    float q = o[0]*o[0] + o[1]*o[1] + o[2]*o[2] + o[3]*o[3];
    #pragma unroll
    for (int off = 32; off > 0; off >>= 1) { s += __shfl_xor(s, off); q += __shfl_xor(q, off); }
    __shared__ float rs[4], rq[4];
    if (lane == 0) { rs[wid] = s; rq[wid] = q; }
    __syncthreads();
    s = rs[0] + rs[1] + rs[2] + rs[3];
    q = rq[0] + rq[1] + rq[2] + rq[3];
    float mu  = s * (1.f/1024.f);
    float var = q * (1.f/1024.f) - mu*mu;
    float inv = rsqrtf(var + 1e-5f);
    float4 lw = ((const float4*)lnw)[tid];
    float4 lb = ((const float4*)lnb)[tid];
    float4 y;
    y.x = (o[0] - mu)*inv*lw.x + lb.x;
    y.y = (o[1] - mu)*inv*lw.y + lb.y;
    y.z = (o[2] - mu)*inv*lw.z + lb.z;
    y.w = (o[3] - mu)*inv*lw.w + lb.w;
    ((float4*)(out + row*Dd))[tid] = y;
}

extern "C" void kernel_launch(void* const* d_in, const int* in_sizes, int n_in,
                              void* d_out, int out_size, void* d_ws, size_t ws_size,
                              hipStream_t stream)
{
    const float* X     = (const float*)d_in[0];
    const float* posW  = (const float*)d_in[1];
    const float* posB  = (const float*)d_in[2];
    const float* pbias = (const float*)d_in[3];
    const float* spos  = (const float*)d_in[4];
    const float* lsc   = (const float*)d_in[5];
    const float* qW    = (const float*)d_in[6];
    const float* kW    = (const float*)d_in[7];
    const float* vW    = (const float*)d_in[8];
    const float* gates = (const float*)d_in[9];
    const float* rwp   = (const float*)d_in[10];
    const float* lnw   = (const float*)d_in[11];
    const float* lnb   = (const float*)d_in[12];

    char* ws = (char*)d_ws;
    size_t off = 0;
    float* w_infl = (float*)(ws + off); off += (size_t)Bb*Ss*Nn*4;
    bf16*  Xb     = (bf16*) (ws + off); off += (size_t)Bb*Ss*Dd*2;
    bf16*  Wt     = (bf16*) (ws + off); off += (size_t)3*Dd*Dd*2;
    bf16*  Q      = (bf16*) (ws + off); off += (size_t)Bb*Ss*Dd*2;
    bf16*  Kmat   = (bf16*) (ws + off); off += (size_t)Bb*Ss*Dd*2;
    bf16*  V      = (bf16*) (ws + off); off += (size_t)Bb*Ss*Dd*2;
    bf16*  Vt     = (bf16*) (ws + off); off += (size_t)Bb*Dd*Ss*2;
    float* qk     = (float*)(ws + off); off += (size_t)Bb*Ss*Ss*4;
    bf16*  Aav    = (bf16*) (ws + off); off += (size_t)Bb*Ss*Ss*2;
    float* comb   = (float*)(ws + off); off += (size_t)Bb*Ss*Dd*4;
    (void)Kmat; (void)ws_size;

    dim3 blk(256);
    // 1) weight transposes + cast -> W^T [out_dim][in_dim] bf16
    k_transpose_f2b<<<dim3(16,16,1), blk, 0, stream>>>(qW, Wt,           Dd, Dd);
    k_transpose_f2b<<<dim3(16,16,1), blk, 0, stream>>>(kW, Wt + Dd*Dd,   Dd, Dd);
    k_transpose_f2b<<<dim3(16,16,1), blk, 0, stream>>>(vW, Wt + 2*Dd*Dd, Dd, Dd);
    // 2) X -> bf16
    k_cast<<<dim3(Bb*Ss*Dd/1024), blk, 0, stream>>>(X, Xb);
    // 3) positions + influence weights (f32 path)
    k_pos_influence<<<dim3(Bb*Ss/4), blk, 0, stream>>>(X, posW, posB, pbias, spos, lsc, w_infl);
    // 4) Q,K,V = Xb @ W^T (one launch, z over the 3 weights)
    k_gemm_bt<1><<<dim3(8,16,3), blk, 0, stream>>>(Xb, Wt, (void*)Q,
        Bb*Ss, Dd, Dd, 0L, (long)Dd*Dd, (long)Bb*Ss*Dd, 1.f, 0);
    // 5) V^T per batch
    k_transpose_bf<<<dim3(16,16,2), blk, 0, stream>>>(V, Vt, Ss, Dd, (long)Ss*Dd, (long)Dd*Ss);
    // 6) qk = Q @ K^T / sqrt(D), lower-tri tiles only
    k_gemm_bt<0><<<dim3(8,8,2), blk, 0, stream>>>(Q, Kmat, (void*)qk,
        Ss, Ss, Dd, (long)Ss*Dd, (long)Ss*Dd, (long)Ss*Ss, 0.03125f, 1);
    // 7) per-row 16-splat softmax + gated average -> A_avg
    k_softmax_avg<<<dim3(Ss, Bb), blk, 0, stream>>>(qk, w_infl, gates, Aav);
    // 8) combined = A_avg @ V (K-loop bounded by diagonal)
    k_gemm_bt<0><<<dim3(8,8,2), blk, 0, stream>>>(Aav, Vt, (void*)comb,
        Ss, Dd, Ss, (long)Ss*Ss, (long)Dd*Ss, (long)Ss*Dd, 1.f, 2);
    // 9) residual + LayerNorm
    k_epilogue<<<dim3(Bb*Ss), blk, 0, stream>>>(comb, X, lnw, lnb, rwp, (float*)d_out);
}

// Round 3
// 240.536 us; speedup vs baseline: 1.1845x; 1.1845x over previous
//
#include <hip/hip_runtime.h>
#include <hip/hip_bf16.h>
#include <hip/hip_fp16.h>

using bf16 = __hip_bfloat16;
typedef __attribute__((ext_vector_type(8))) short short8;
typedef __attribute__((ext_vector_type(4))) float f32x4;

static constexpr int Bb = 2, Ss = 1024, Dd = 1024, Ee = 64, Nn = 16;

__device__ __forceinline__ unsigned short f2bfr(float f) {
    __hip_bfloat16 h = __float2bfloat16(f);
    return *reinterpret_cast<unsigned short*>(&h);
}

// ---------------- f32 -> bf16 elementwise cast (X) ----------------
__global__ __launch_bounds__(256) void k_cast(
    const float* __restrict__ in, bf16* __restrict__ out)
{
    int i = blockIdx.x * 256 + threadIdx.x;
    float4 v = ((const float4*)in)[i];
    ushort4 y;
    y.x = f2bfr(v.x); y.y = f2bfr(v.y); y.z = f2bfr(v.z); y.w = f2bfr(v.w);
    ((ushort4*)out)[i] = y;
}

// ---------------- f32 transpose+cast: out_bf16[c][r] = in_f32[r][c] ----------------
__global__ __launch_bounds__(256) void k_transpose_f2b(
    const float* __restrict__ in, bf16* __restrict__ out, int R, int C)
{
    __shared__ float tile[64][65];
    int tx = threadIdx.x & 63, ty = threadIdx.x >> 6;
    int r0 = blockIdx.y * 64, c0 = blockIdx.x * 64;
    #pragma unroll
    for (int i = 0; i < 16; ++i)
        tile[ty + i*4][tx] = in[(long)(r0 + ty + i*4)*C + c0 + tx];
    __syncthreads();
    #pragma unroll
    for (int i = 0; i < 16; ++i)
        out[(long)(c0 + ty + i*4)*R + r0 + tx] = __float2bfloat16(tile[tx][ty + i*4]);
}

// ---------------- bf16 transpose: out[c][r] = in[r][c] ----------------
__global__ __launch_bounds__(256) void k_transpose_bf(
    const bf16* __restrict__ in, bf16* __restrict__ out,
    int R, int C, long sIn, long sOut)
{
    in  += (long)blockIdx.z * sIn;
    out += (long)blockIdx.z * sOut;
    __shared__ bf16 tile[64][65];
    int tx = threadIdx.x & 63, ty = threadIdx.x >> 6;
    int r0 = blockIdx.y * 64, c0 = blockIdx.x * 64;
    #pragma unroll
    for (int i = 0; i < 16; ++i)
        tile[ty + i*4][tx] = in[(long)(r0 + ty + i*4)*C + c0 + tx];
    __syncthreads();
    #pragma unroll
    for (int i = 0; i < 16; ++i)
        out[(long)(c0 + ty + i*4)*R + r0 + tx] = tile[tx][ty + i*4];
}

// ---- pos GEMM (MFMA) + tanh/bias + fused splat influence -> w[2048][16] f32 ----
// Xb: [2048][1024] bf16, WpT: [64][1024] bf16 (= pos_W^T). One block = 64 rows.
__global__ __launch_bounds__(256) void k_pos_gemm(
    const bf16* __restrict__ Xb, const bf16* __restrict__ WpT,
    const float* __restrict__ pb, const float* __restrict__ pbias,
    const float* __restrict__ spos, const float* __restrict__ lsc,
    float* __restrict__ wout)
{
    __shared__ short lA[64*32];
    __shared__ short lB[64*32];
    __shared__ float P[64][65];
    __shared__ float sp[16][65];

    int tid = threadIdx.x, wid = tid >> 6, lane = tid & 63;
    int r16 = lane & 15, quad = lane >> 4;
    int m0 = blockIdx.x * 64;

    for (int idx = tid; idx < 16*64; idx += 256)
        sp[idx >> 6][idx & 63] = spos[idx];

    f32x4 acc[4];
    #pragma unroll
    for (int j = 0; j < 4; ++j)
        #pragma unroll
        for (int c = 0; c < 4; ++c) acc[j][c] = 0.f;

    // staging: 256 16B chunks per 64x32 tile; chunk c -> row=c>>2, koff=(c&3)*8
    int ra = tid >> 2, ka = (tid & 3) * 8;
    const short* Ag = (const short*)Xb;
    const short* Bg = (const short*)WpT;

    for (int k0 = 0; k0 < Dd; k0 += 32) {
        __syncthreads();
        __builtin_amdgcn_global_load_lds(
            (const __attribute__((address_space(1))) void*)(Ag + (long)(m0+ra)*Dd + k0 + ka),
            (__attribute__((address_space(3))) void*)(lA + tid*8), 16, 0, 0);
        __builtin_amdgcn_global_load_lds(
            (const __attribute__((address_space(1))) void*)(Bg + (long)ra*Dd + k0 + ka),
            (__attribute__((address_space(3))) void*)(lB + tid*8), 16, 0, 0);
        __syncthreads();

        short8 af = *(const short8*)(lA + (wid*16 + r16)*32 + quad*8);
        #pragma unroll
        for (int j = 0; j < 4; ++j) {
            short8 bfv = *(const short8*)(lB + (j*16 + r16)*32 + quad*8);
            acc[j] = __builtin_amdgcn_mfma_f32_16x16x32_bf16(af, bfv, acc[j], 0, 0, 0);
        }
    }

    // epilogue: tanh(acc + pb) + pbias -> P in LDS
    #pragma unroll
    for (int j = 0; j < 4; ++j)
        #pragma unroll
        for (int rr = 0; rr < 4; ++rr) {
            int rl  = wid*16 + quad*4 + rr;       // local row 0..63
            int col = j*16 + r16;                 // 0..63
            int srow = (m0 + rl) & (Ss - 1);
            P[rl][col] = tanhf(acc[j][rr] + pb[col]) + pbias[srow*Ee + col];
        }
    __syncthreads();

    // influence: thread -> splat n = tid&15, rows 4*(tid>>4)..+3
    int n  = tid & 15;
    int rb = (tid >> 4) * 4;
    float sc = __expf(lsc[n]);
    sc = fminf(fmaxf(sc, 0.3f), 2.0f);
    float inv2 = -0.5f / (sc * sc);
    #pragma unroll
    for (int rr = 0; rr < 4; ++rr) {
        int row = rb + rr;
        float d2 = 0.f;
        #pragma unroll 16
        for (int e = 0; e < 64; ++e) {
            float df = P[row][e] - sp[n][e];
            d2 += df * df;
        }
        float infl = fmaxf(__expf(d2 * inv2), 0.01f);
        wout[(long)(m0 + row)*Nn + n] = infl;
    }
}

// ---------------- C = scale * A @ Bt^T  (bf16 in, K-contiguous) ----------------
// causal=1: skip tiles with n0 > m0. causal=2: K-loop bound m0+128 (A lower-tri).
template<int OUT_BF16>
__global__ __launch_bounds__(256) void k_gemm_bt(
    const bf16* __restrict__ A, const bf16* __restrict__ Bt, void* __restrict__ Cv,
    int M, int N, int K, long sA, long sB, long sC, float scale, int causal)
{
    int z = blockIdx.z;
    const bf16* Ab = A  + (long)z * sA;
    const bf16* Bw = Bt + (long)z * sB;
    int bm = blockIdx.y, bn = blockIdx.x;
    if (causal == 1 && bn > bm) return;
    int m0 = bm * 128, n0 = bn * 128;
    int kEnd = (causal == 2) ? ((m0 + 128 < K) ? m0 + 128 : K) : K;

    __shared__ short lA[128*32];
    __shared__ short lB[128*32];
    int tid = threadIdx.x, wid = tid >> 6, lane = tid & 63;
    int wm = (wid >> 1)*64, wn = (wid & 1)*64;
    int r16 = lane & 15, quad = lane >> 4;

    f32x4 acc[4][4];
    #pragma unroll
    for (int i = 0; i < 4; ++i)
        #pragma unroll
        for (int j = 0; j < 4; ++j)
            #pragma unroll
            for (int c = 0; c < 4; ++c) acc[i][j][c] = 0.f;

    int c0 = wid*64 + lane, c1 = c0 + 256;
    int ra0 = c0 >> 2, ka0 = (c0 & 3)*8;
    int ra1 = c1 >> 2, ka1 = (c1 & 3)*8;
    const short* Ag = (const short*)Ab;
    const short* Bg = (const short*)Bw;

    for (int k0 = 0; k0 < kEnd; k0 += 32) {
        __syncthreads();
        __builtin_amdgcn_global_load_lds(
            (const __attribute__((address_space(1))) void*)(Ag + (long)(m0+ra0)*K + k0 + ka0),
            (__attribute__((address_space(3))) void*)(lA + c0*8), 16, 0, 0);
        __builtin_amdgcn_global_load_lds(
            (const __attribute__((address_space(1))) void*)(Ag + (long)(m0+ra1)*K + k0 + ka1),
            (__attribute__((address_space(3))) void*)(lA + c1*8), 16, 0, 0);
        __builtin_amdgcn_global_load_lds(
            (const __attribute__((address_space(1))) void*)(Bg + (long)(n0+ra0)*K + k0 + ka0),
            (__attribute__((address_space(3))) void*)(lB + c0*8), 16, 0, 0);
        __builtin_amdgcn_global_load_lds(
            (const __attribute__((address_space(1))) void*)(Bg + (long)(n0+ra1)*K + k0 + ka1),
            (__attribute__((address_space(3))) void*)(lB + c1*8), 16, 0, 0);
        __syncthreads();

        short8 af[4], bfv[4];
        #pragma unroll
        for (int i = 0; i < 4; ++i) af[i]  = *(const short8*)(lA + (wm + i*16 + r16)*32 + quad*8);
        #pragma unroll
        for (int j = 0; j < 4; ++j) bfv[j] = *(const short8*)(lB + (wn + j*16 + r16)*32 + quad*8);
        #pragma unroll
        for (int i = 0; i < 4; ++i)
            #pragma unroll
            for (int j = 0; j < 4; ++j)
                acc[i][j] = __builtin_amdgcn_mfma_f32_16x16x32_bf16(af[i], bfv[j], acc[i][j], 0, 0, 0);
    }

    if (OUT_BF16) {
        bf16* C = (bf16*)Cv + (long)z * sC;
        #pragma unroll
        for (int i = 0; i < 4; ++i)
            #pragma unroll
            for (int j = 0; j < 4; ++j)
                #pragma unroll
                for (int rr = 0; rr < 4; ++rr) {
                    long row = m0 + wm + i*16 + quad*4 + rr;
                    long col = n0 + wn + j*16 + r16;
                    C[row*N + col] = __float2bfloat16(acc[i][j][rr] * scale);
                }
    } else {
        float* C = (float*)Cv + (long)z * sC;
        #pragma unroll
        for (int i = 0; i < 4; ++i)
            #pragma unroll
            for (int j = 0; j < 4; ++j)
                #pragma unroll
                for (int rr = 0; rr < 4; ++rr) {
                    long row = m0 + wm + i*16 + quad*4 + rr;
                    long col = n0 + wn + j*16 + r16;
                    C[row*N + col] = acc[i][j][rr] * scale;
                }
    }
}

// ---------------- block reduce helpers (16 lanes-worth of scalars) ----------------
__device__ __forceinline__ void reduce16_max(float* v, float (*red)[16], int wid, int lane) {
    #pragma unroll
    for (int n = 0; n < 16; ++n)
        #pragma unroll
        for (int off = 32; off > 0; off >>= 1)
            v[n] = fmaxf(v[n], __shfl_xor(v[n], off));
    if (lane == 0) {
        #pragma unroll
        for (int n = 0; n < 16; ++n) red[wid][n] = v[n];
    }
    __syncthreads();
    #pragma unroll
    for (int n = 0; n < 16; ++n)
        v[n] = fmaxf(fmaxf(red[0][n], red[1][n]), fmaxf(red[2][n], red[3][n]));
}
__device__ __forceinline__ void reduce16_sum(float* v, float (*red)[16], int wid, int lane) {
    #pragma unroll
    for (int n = 0; n < 16; ++n)
        #pragma unroll
        for (int off = 32; off > 0; off >>= 1)
            v[n] += __shfl_xor(v[n], off);
    if (lane == 0) {
        #pragma unroll
        for (int n = 0; n < 16; ++n) red[wid][n] = v[n];
    }
    __syncthreads();
    #pragma unroll
    for (int n = 0; n < 16; ++n)
        v[n] = red[0][n] + red[1][n] + red[2][n] + red[3][n];
}

// ---------------- per-row: 16-splat softmax + gated average -> A_avg (bf16) ----------------
__global__ __launch_bounds__(256) void k_softmax_avg(
    const float* __restrict__ qk, const float* __restrict__ w,
    const float* __restrict__ gates, bf16* __restrict__ Aout)
{
    int i = blockIdx.x, b = blockIdx.y;
    const float* qrow = qk + ((long)b*Ss + i)*Ss;
    const float* wb   = w  + (long)b*Ss*Nn;
    bf16* arow        = Aout + ((long)b*Ss + i)*Ss;

    __shared__ __half2 wt[1024][9];   // padded stride to break bank conflicts
    __shared__ float wiS[16];
    __shared__ float redA[4][16];
    __shared__ float redB[4][16];

    int tid = threadIdx.x, wid = tid >> 6, lane = tid & 63;

    for (int j = tid; j <= i; j += 256) {
        const float* src = wb + j*16;
        #pragma unroll
        for (int h = 0; h < 8; ++h)
            wt[j][h] = __float22half2_rn(make_float2(src[2*h], src[2*h + 1]));
    }
    if (tid < 16) wiS[tid] = wb[(long)i*16 + tid];
    __syncthreads();

    float wiR[16], m[16], l[16];
    #pragma unroll
    for (int n = 0; n < 16; ++n) { wiR[n] = wiS[n]; m[n] = -1e30f; l[n] = 0.f; }

    for (int j = tid; j <= i; j += 256) {
        float q = qrow[j];
        #pragma unroll
        for (int h = 0; h < 8; ++h) {
            float2 f = __half22float2(wt[j][h]);
            m[2*h]     = fmaxf(m[2*h],     wiR[2*h]     * f.x * q);
            m[2*h + 1] = fmaxf(m[2*h + 1], wiR[2*h + 1] * f.y * q);
        }
    }
    reduce16_max(m, redA, wid, lane);

    for (int j = tid; j <= i; j += 256) {
        float q = qrow[j];
        #pragma unroll
        for (int h = 0; h < 8; ++h) {
            float2 f = __half22float2(wt[j][h]);
            l[2*h]     += __expf(wiR[2*h]     * f.x * q - m[2*h]);
            l[2*h + 1] += __expf(wiR[2*h + 1] * f.y * q - m[2*h + 1]);
        }
    }
    reduce16_sum(l, redB, wid, lane);

    float coef[16];
    #pragma unroll
    for (int n = 0; n < 16; ++n) {
        float g  = gates[n];
        float sg = 1.f / (1.f + __expf(-g));
        coef[n]  = sg / (16.f * l[n]);
    }

    for (int j = tid; j < Ss; j += 256) {
        float a = 0.f;
        if (j <= i) {
            float q = qrow[j];
            #pragma unroll
            for (int h = 0; h < 8; ++h) {
                float2 f = __half22float2(wt[j][h]);
                a += coef[2*h]     * __expf(wiR[2*h]     * f.x * q - m[2*h]);
                a += coef[2*h + 1] * __expf(wiR[2*h + 1] * f.y * q - m[2*h + 1]);
            }
        }
        arow[j] = __float2bfloat16(a);
    }
}

// ---------------- residual + LayerNorm epilogue (all f32) ----------------
__global__ __launch_bounds__(256) void k_epilogue(
    const float* __restrict__ comb, const float* __restrict__ X,
    const float* __restrict__ lnw, const float* __restrict__ lnb,
    const float* __restrict__ rwp, float* __restrict__ out)
{
    long row = blockIdx.x;
    int tid = threadIdx.x, wid = tid >> 6, lane = tid & 63;
    float rw = 1.f / (1.f + __expf(-rwp[0]));
    float4 cv = ((const float4*)(comb + row*Dd))[tid];
    float4 xv = ((const float4*)(X + row*Dd))[tid];
    float o[4];
    o[0] = rw * xv.x + (1.f - rw) * cv.x;
    o[1] = rw * xv.y + (1.f - rw) * cv.y;
    o[2] = rw * xv.z + (1.f - rw) * cv.z;
    o[3] = rw * xv.w + (1.f - rw) * cv.w;
    float s = o[0] + o[1] + o[2] + o[3];
    float q = o[0]*o[0] + o[1]*o[1] + o[2]*o[2] + o[3]*o[3];
    #pragma unroll
    for (int off = 32; off > 0; off >>= 1) { s += __shfl_xor(s, off); q += __shfl_xor(q, off); }
    __shared__ float rs[4], rq[4];
    if (lane == 0) { rs[wid] = s; rq[wid] = q; }
    __syncthreads();
    s = rs[0] + rs[1] + rs[2] + rs[3];
    q = rq[0] + rq[1] + rq[2] + rq[3];
    float mu  = s * (1.f/1024.f);
    float var = q * (1.f/1024.f) - mu*mu;
    float inv = rsqrtf(var + 1e-5f);
    float4 lw = ((const float4*)lnw)[tid];
    float4 lb = ((const float4*)lnb)[tid];
    float4 y;
    y.x = (o[0] - mu)*inv*lw.x + lb.x;
    y.y = (o[1] - mu)*inv*lw.y + lb.y;
    y.z = (o[2] - mu)*inv*lw.z + lb.z;
    y.w = (o[3] - mu)*inv*lw.w + lb.w;
    ((float4*)(out + row*Dd))[tid] = y;
}

extern "C" void kernel_launch(void* const* d_in, const int* in_sizes, int n_in,
                              void* d_out, int out_size, void* d_ws, size_t ws_size,
                              hipStream_t stream)
{
    const float* X     = (const float*)d_in[0];
    const float* posW  = (const float*)d_in[1];
    const float* posB  = (const float*)d_in[2];
    const float* pbias = (const float*)d_in[3];
    const float* spos  = (const float*)d_in[4];
    const float* lsc   = (const float*)d_in[5];
    const float* qW    = (const float*)d_in[6];
    const float* kW    = (const float*)d_in[7];
    const float* vW    = (const float*)d_in[8];
    const float* gates = (const float*)d_in[9];
    const float* rwp   = (const float*)d_in[10];
    const float* lnw   = (const float*)d_in[11];
    const float* lnb   = (const float*)d_in[12];

    char* ws = (char*)d_ws;
    size_t off = 0;
    float* w_infl = (float*)(ws + off); off += (size_t)Bb*Ss*Nn*4;
    bf16*  Xb     = (bf16*) (ws + off); off += (size_t)Bb*Ss*Dd*2;
    bf16*  Wt     = (bf16*) (ws + off); off += (size_t)3*Dd*Dd*2;
    bf16*  WpT    = (bf16*) (ws + off); off += (size_t)Ee*Dd*2;
    bf16*  Q      = (bf16*) (ws + off); off += (size_t)Bb*Ss*Dd*2;
    bf16*  Kmat   = (bf16*) (ws + off); off += (size_t)Bb*Ss*Dd*2;
    bf16*  V      = (bf16*) (ws + off); off += (size_t)Bb*Ss*Dd*2;
    bf16*  Vt     = (bf16*) (ws + off); off += (size_t)Bb*Dd*Ss*2;
    float* qk     = (float*)(ws + off); off += (size_t)Bb*Ss*Ss*4;
    bf16*  Aav    = (bf16*) (ws + off); off += (size_t)Bb*Ss*Ss*2;
    float* comb   = (float*)(ws + off); off += (size_t)Bb*Ss*Dd*4;
    (void)Kmat; (void)ws_size;

    dim3 blk(256);
    // 1) weight transposes + cast -> bf16 [out_dim][in_dim]
    k_transpose_f2b<<<dim3(16,16,1), blk, 0, stream>>>(qW, Wt,           Dd, Dd);
    k_transpose_f2b<<<dim3(16,16,1), blk, 0, stream>>>(kW, Wt + Dd*Dd,   Dd, Dd);
    k_transpose_f2b<<<dim3(16,16,1), blk, 0, stream>>>(vW, Wt + 2*Dd*Dd, Dd, Dd);
    k_transpose_f2b<<<dim3(1,16,1),  blk, 0, stream>>>(posW, WpT,        Dd, Ee);
    // 2) X -> bf16
    k_cast<<<dim3(Bb*Ss*Dd/1024), blk, 0, stream>>>(X, Xb);
    // 3) MFMA pos GEMM + fused influence
    k_pos_gemm<<<dim3(Bb*Ss/64), blk, 0, stream>>>(Xb, WpT, posB, pbias, spos, lsc, w_infl);
    // 4) Q,K,V = Xb @ W^T (one launch, z over the 3 weights)
    k_gemm_bt<1><<<dim3(8,16,3), blk, 0, stream>>>(Xb, Wt, (void*)Q,
        Bb*Ss, Dd, Dd, 0L, (long)Dd*Dd, (long)Bb*Ss*Dd, 1.f, 0);
    // 5) V^T per batch
    k_transpose_bf<<<dim3(16,16,2), blk, 0, stream>>>(V, Vt, Ss, Dd, (long)Ss*Dd, (long)Dd*Ss);
    // 6) qk = Q @ K^T / sqrt(D), lower-tri tiles only
    k_gemm_bt<0><<<dim3(8,8,2), blk, 0, stream>>>(Q, Kmat, (void*)qk,
        Ss, Ss, Dd, (long)Ss*Dd, (long)Ss*Dd, (long)Ss*Ss, 0.03125f, 1);
    // 7) per-row 16-splat softmax + gated average -> A_avg
    k_softmax_avg<<<dim3(Ss, Bb), blk, 0, stream>>>(qk, w_infl, gates, Aav);
    // 8) combined = A_avg @ V (K-loop bounded by diagonal)
    k_gemm_bt<0><<<dim3(8,8,2), blk, 0, stream>>>(Aav, Vt, (void*)comb,
        Ss, Dd, Ss, (long)Ss*Ss, (long)Dd*Ss, (long)Ss*Dd, 1.f, 2);
    // 9) residual + LayerNorm
    k_epilogue<<<dim3(Bb*Ss), blk, 0, stream>>>(comb, X, lnw, lnb, rwp, (float*)d_out);
}

// Round 4
// 211.996 us; speedup vs baseline: 1.3439x; 1.1346x over previous
//
#include <hip/hip_runtime.h>
#include <hip/hip_bf16.h>
#include <hip/hip_fp16.h>

using bf16 = __hip_bfloat16;
typedef __attribute__((ext_vector_type(8))) short short8;
typedef __attribute__((ext_vector_type(4))) float f32x4;

static constexpr int Bb = 2, Ss = 1024, Dd = 1024, Ee = 64, Nn = 16;

__device__ __forceinline__ unsigned short f2bfr(float f) {
    __hip_bfloat16 h = __float2bfloat16(f);
    return *reinterpret_cast<unsigned short*>(&h);
}

// ---------------- f32 -> bf16 elementwise cast (X) ----------------
__global__ __launch_bounds__(256) void k_cast(
    const float* __restrict__ in, bf16* __restrict__ out)
{
    int i = blockIdx.x * 256 + threadIdx.x;
    float4 v = ((const float4*)in)[i];
    ushort4 y;
    y.x = f2bfr(v.x); y.y = f2bfr(v.y); y.z = f2bfr(v.z); y.w = f2bfr(v.w);
    ((ushort4*)out)[i] = y;
}

// ------- one launch: 3 weight transposes + posW transpose (z-indexed) -------
__global__ __launch_bounds__(256) void k_prep(
    const float* __restrict__ qW, const float* __restrict__ kW,
    const float* __restrict__ vW, const float* __restrict__ posW,
    bf16* __restrict__ Wt, bf16* __restrict__ WpT)
{
    int z = blockIdx.z;
    const float* in; bf16* out; int C = Dd;
    if      (z == 0) { in = qW;   out = Wt; }
    else if (z == 1) { in = kW;   out = Wt + Dd*Dd; }
    else if (z == 2) { in = vW;   out = Wt + 2*Dd*Dd; }
    else             { in = posW; out = WpT; C = Ee; if (blockIdx.x) return; }
    const int R = Dd;
    __shared__ float tile[64][65];
    int tx = threadIdx.x & 63, ty = threadIdx.x >> 6;
    int r0 = blockIdx.y * 64, c0 = blockIdx.x * 64;
    #pragma unroll
    for (int i = 0; i < 16; ++i)
        tile[ty + i*4][tx] = in[(long)(r0 + ty + i*4)*C + c0 + tx];
    __syncthreads();
    #pragma unroll
    for (int i = 0; i < 16; ++i)
        out[(long)(c0 + ty + i*4)*R + r0 + tx] = __float2bfloat16(tile[tx][ty + i*4]);
}

// ---------------- bf16 transpose: out[c][r] = in[r][c] ----------------
__global__ __launch_bounds__(256) void k_transpose_bf(
    const bf16* __restrict__ in, bf16* __restrict__ out,
    int R, int C, long sIn, long sOut)
{
    in  += (long)blockIdx.z * sIn;
    out += (long)blockIdx.z * sOut;
    __shared__ bf16 tile[64][65];
    int tx = threadIdx.x & 63, ty = threadIdx.x >> 6;
    int r0 = blockIdx.y * 64, c0 = blockIdx.x * 64;
    #pragma unroll
    for (int i = 0; i < 16; ++i)
        tile[ty + i*4][tx] = in[(long)(r0 + ty + i*4)*C + c0 + tx];
    __syncthreads();
    #pragma unroll
    for (int i = 0; i < 16; ++i)
        out[(long)(c0 + ty + i*4)*R + r0 + tx] = tile[tx][ty + i*4];
}

// ---- pos GEMM (MFMA) + tanh/bias + fused splat influence -> w[2048][16] f32 ----
__global__ __launch_bounds__(256) void k_pos_gemm(
    const bf16* __restrict__ Xb, const bf16* __restrict__ WpT,
    const float* __restrict__ pb, const float* __restrict__ pbias,
    const float* __restrict__ spos, const float* __restrict__ lsc,
    float* __restrict__ wout)
{
    __shared__ short lA[64*32];
    __shared__ short lB[64*32];
    __shared__ float P[64][65];
    __shared__ float sp[16][65];

    int tid = threadIdx.x, wid = tid >> 6, lane = tid & 63;
    int r16 = lane & 15, quad = lane >> 4;
    int m0 = blockIdx.x * 64;

    for (int idx = tid; idx < 16*64; idx += 256)
        sp[idx >> 6][idx & 63] = spos[idx];

    f32x4 acc[4];
    #pragma unroll
    for (int j = 0; j < 4; ++j)
        #pragma unroll
        for (int c = 0; c < 4; ++c) acc[j][c] = 0.f;

    int ra = tid >> 2, ka = (tid & 3) * 8;
    const short* Ag = (const short*)Xb;
    const short* Bg = (const short*)WpT;

    for (int k0 = 0; k0 < Dd; k0 += 32) {
        __syncthreads();
        __builtin_amdgcn_global_load_lds(
            (const __attribute__((address_space(1))) void*)(Ag + (long)(m0+ra)*Dd + k0 + ka),
            (__attribute__((address_space(3))) void*)(lA + tid*8), 16, 0, 0);
        __builtin_amdgcn_global_load_lds(
            (const __attribute__((address_space(1))) void*)(Bg + (long)ra*Dd + k0 + ka),
            (__attribute__((address_space(3))) void*)(lB + tid*8), 16, 0, 0);
        __syncthreads();

        short8 af = *(const short8*)(lA + (wid*16 + r16)*32 + quad*8);
        #pragma unroll
        for (int j = 0; j < 4; ++j) {
            short8 bfv = *(const short8*)(lB + (j*16 + r16)*32 + quad*8);
            acc[j] = __builtin_amdgcn_mfma_f32_16x16x32_bf16(af, bfv, acc[j], 0, 0, 0);
        }
    }

    #pragma unroll
    for (int j = 0; j < 4; ++j)
        #pragma unroll
        for (int rr = 0; rr < 4; ++rr) {
            int rl  = wid*16 + quad*4 + rr;
            int col = j*16 + r16;
            int srow = (m0 + rl) & (Ss - 1);
            P[rl][col] = tanhf(acc[j][rr] + pb[col]) + pbias[srow*Ee + col];
        }
    __syncthreads();

    int n  = tid & 15;
    int rb = (tid >> 4) * 4;
    float sc = __expf(lsc[n]);
    sc = fminf(fmaxf(sc, 0.3f), 2.0f);
    float inv2 = -0.5f / (sc * sc);
    #pragma unroll
    for (int rr = 0; rr < 4; ++rr) {
        int row = rb + rr;
        float d2 = 0.f;
        #pragma unroll 16
        for (int e = 0; e < 64; ++e) {
            float df = P[row][e] - sp[n][e];
            d2 += df * df;
        }
        float infl = fmaxf(__expf(d2 * inv2), 0.01f);
        wout[(long)(m0 + row)*Nn + n] = infl;
    }
}

// -------- C = scale * A @ Bt^T, 64x128 tile (4 waves of 64x32) --------
// causal=1: skip tiles with n0 > m0+63. causal=2: K bound m0+64 (A lower-tri).
template<int OUT_BF16>
__global__ __launch_bounds__(256) void k_gemm64(
    const bf16* __restrict__ A, const bf16* __restrict__ Bt, void* __restrict__ Cv,
    int M, int N, int K, long sA, long sB, long sC, float scale, int causal)
{
    int z = blockIdx.z;
    const bf16* Ab = A  + (long)z * sA;
    const bf16* Bw = Bt + (long)z * sB;
    int m0 = blockIdx.y * 64, n0 = blockIdx.x * 128;
    if (causal == 1 && n0 > m0 + 63) return;
    int kEnd = (causal == 2) ? ((m0 + 64 < K) ? m0 + 64 : K) : K;

    __shared__ short lA[64*32];
    __shared__ short lB[128*32];
    int tid = threadIdx.x, wid = tid >> 6, lane = tid & 63;
    int wn = wid * 32;
    int r16 = lane & 15, quad = lane >> 4;

    f32x4 acc[4][2];
    #pragma unroll
    for (int i = 0; i < 4; ++i)
        #pragma unroll
        for (int j = 0; j < 2; ++j)
            #pragma unroll
            for (int c = 0; c < 4; ++c) acc[i][j][c] = 0.f;

    // A: 256 chunks (1/thread); B: 512 chunks (2/thread). chunk c -> row=c>>2, koff=(c&3)*8
    int ra  = tid >> 2, ka  = (tid & 3) * 8;
    int c1  = tid + 256;
    int rb1 = c1 >> 2,  kb1 = (c1 & 3) * 8;
    const short* Ag = (const short*)Ab;
    const short* Bg = (const short*)Bw;

    for (int k0 = 0; k0 < kEnd; k0 += 32) {
        __syncthreads();
        __builtin_amdgcn_global_load_lds(
            (const __attribute__((address_space(1))) void*)(Ag + (long)(m0+ra)*K + k0 + ka),
            (__attribute__((address_space(3))) void*)(lA + tid*8), 16, 0, 0);
        __builtin_amdgcn_global_load_lds(
            (const __attribute__((address_space(1))) void*)(Bg + (long)(n0+ra)*K + k0 + ka),
            (__attribute__((address_space(3))) void*)(lB + tid*8), 16, 0, 0);
        __builtin_amdgcn_global_load_lds(
            (const __attribute__((address_space(1))) void*)(Bg + (long)(n0+rb1)*K + k0 + kb1),
            (__attribute__((address_space(3))) void*)(lB + c1*8), 16, 0, 0);
        __syncthreads();

        short8 af[4], bfv[2];
        #pragma unroll
        for (int i = 0; i < 4; ++i) af[i]  = *(const short8*)(lA + (i*16 + r16)*32 + quad*8);
        #pragma unroll
        for (int j = 0; j < 2; ++j) bfv[j] = *(const short8*)(lB + (wn + j*16 + r16)*32 + quad*8);
        #pragma unroll
        for (int i = 0; i < 4; ++i)
            #pragma unroll
            for (int j = 0; j < 2; ++j)
                acc[i][j] = __builtin_amdgcn_mfma_f32_16x16x32_bf16(af[i], bfv[j], acc[i][j], 0, 0, 0);
    }

    if (OUT_BF16) {
        bf16* C = (bf16*)Cv + (long)z * sC;
        #pragma unroll
        for (int i = 0; i < 4; ++i)
            #pragma unroll
            for (int j = 0; j < 2; ++j)
                #pragma unroll
                for (int rr = 0; rr < 4; ++rr) {
                    long row = m0 + i*16 + quad*4 + rr;
                    long col = n0 + wn + j*16 + r16;
                    C[row*N + col] = __float2bfloat16(acc[i][j][rr] * scale);
                }
    } else {
        float* C = (float*)Cv + (long)z * sC;
        #pragma unroll
        for (int i = 0; i < 4; ++i)
            #pragma unroll
            for (int j = 0; j < 2; ++j)
                #pragma unroll
                for (int rr = 0; rr < 4; ++rr) {
                    long row = m0 + i*16 + quad*4 + rr;
                    long col = n0 + wn + j*16 + r16;
                    C[row*N + col] = acc[i][j][rr] * scale;
                }
    }
}

// ---- 4 rows per block (1 wave/row): 16-splat softmax + gated avg -> A_avg ----
__global__ __launch_bounds__(256) void k_softmax_avg4(
    const float* __restrict__ qk, const float* __restrict__ w,
    const float* __restrict__ gates, bf16* __restrict__ Aout)
{
    int base = blockIdx.x * 4, b = blockIdx.y;
    int imax = base + 3;
    const float* wb = w + (long)b*Ss*Nn;

    __shared__ __half2 wt[1024][9];   // stride 9 half2 = 18 banks: conflict-light
    __shared__ float wi4[4][16];

    int tid = threadIdx.x, wid = tid >> 6, lane = tid & 63;

    for (int j = tid; j <= imax; j += 256) {
        const float* src = wb + j*16;
        #pragma unroll
        for (int h = 0; h < 8; ++h)
            wt[j][h] = __float22half2_rn(make_float2(src[2*h], src[2*h + 1]));
    }
    if (tid < 64) wi4[tid >> 4][tid & 15] = wb[(long)(base + (tid >> 4))*16 + (tid & 15)];
    __syncthreads();

    int i = base + wid;                        // this wave's row
    const float* qrow = qk + ((long)b*Ss + i)*Ss;
    bf16* arow        = Aout + ((long)b*Ss + i)*Ss;

    float wiR[16], m[16], l[16];
    #pragma unroll
    for (int n = 0; n < 16; ++n) { wiR[n] = wi4[wid][n]; m[n] = -1e30f; l[n] = 0.f; }

    // pass 1: max
    for (int j = lane; j <= i; j += 64) {
        float q = qrow[j];
        #pragma unroll
        for (int h = 0; h < 8; ++h) {
            float2 f = __half22float2(wt[j][h]);
            m[2*h]     = fmaxf(m[2*h],     wiR[2*h]     * f.x * q);
            m[2*h + 1] = fmaxf(m[2*h + 1], wiR[2*h + 1] * f.y * q);
        }
    }
    #pragma unroll
    for (int n = 0; n < 16; ++n)
        #pragma unroll
        for (int off = 32; off > 0; off >>= 1)
            m[n] = fmaxf(m[n], __shfl_xor(m[n], off));

    // pass 2: denominator
    for (int j = lane; j <= i; j += 64) {
        float q = qrow[j];
        #pragma unroll
        for (int h = 0; h < 8; ++h) {
            float2 f = __half22float2(wt[j][h]);
            l[2*h]     += __expf(wiR[2*h]     * f.x * q - m[2*h]);
            l[2*h + 1] += __expf(wiR[2*h + 1] * f.y * q - m[2*h + 1]);
        }
    }
    #pragma unroll
    for (int n = 0; n < 16; ++n)
        #pragma unroll
        for (int off = 32; off > 0; off >>= 1)
            l[n] += __shfl_xor(l[n], off);

    float coef[16];
    #pragma unroll
    for (int n = 0; n < 16; ++n) {
        float g  = gates[n];
        float sg = 1.f / (1.f + __expf(-g));
        coef[n]  = sg / (16.f * l[n]);
    }

    // pass 3: averaged attention row (zeros beyond diagonal)
    for (int j = lane; j < Ss; j += 64) {
        float a = 0.f;
        if (j <= i) {
            float q = qrow[j];
            #pragma unroll
            for (int h = 0; h < 8; ++h) {
                float2 f = __half22float2(wt[j][h]);
                a += coef[2*h]     * __expf(wiR[2*h]     * f.x * q - m[2*h]);
                a += coef[2*h + 1] * __expf(wiR[2*h + 1] * f.y * q - m[2*h + 1]);
            }
        }
        arow[j] = __float2bfloat16(a);
    }
}

// ---------------- residual + LayerNorm epilogue (all f32) ----------------
__global__ __launch_bounds__(256) void k_epilogue(
    const float* __restrict__ comb, const float* __restrict__ X,
    const float* __restrict__ lnw, const float* __restrict__ lnb,
    const float* __restrict__ rwp, float* __restrict__ out)
{
    long row = blockIdx.x;
    int tid = threadIdx.x, wid = tid >> 6, lane = tid & 63;
    float rw = 1.f / (1.f + __expf(-rwp[0]));
    float4 cv = ((const float4*)(comb + row*Dd))[tid];
    float4 xv = ((const float4*)(X + row*Dd))[tid];
    float o[4];
    o[0] = rw * xv.x + (1.f - rw) * cv.x;
    o[1] = rw * xv.y + (1.f - rw) * cv.y;
    o[2] = rw * xv.z + (1.f - rw) * cv.z;
    o[3] = rw * xv.w + (1.f - rw) * cv.w;
    float s = o[0] + o[1] + o[2] + o[3];
    float q = o[0]*o[0] + o[1]*o[1] + o[2]*o[2] + o[3]*o[3];
    #pragma unroll
    for (int off = 32; off > 0; off >>= 1) { s += __shfl_xor(s, off); q += __shfl_xor(q, off); }
    __shared__ float rs[4], rq[4];
    if (lane == 0) { rs[wid] = s; rq[wid] = q; }
    __syncthreads();
    s = rs[0] + rs[1] + rs[2] + rs[3];
    q = rq[0] + rq[1] + rq[2] + rq[3];
    float mu  = s * (1.f/1024.f);
    float var = q * (1.f/1024.f) - mu*mu;
    float inv = rsqrtf(var + 1e-5f);
    float4 lw = ((const float4*)lnw)[tid];
    float4 lb = ((const float4*)lnb)[tid];
    float4 y;
    y.x = (o[0] - mu)*inv*lw.x + lb.x;
    y.y = (o[1] - mu)*inv*lw.y + lb.y;
    y.z = (o[2] - mu)*inv*lw.z + lb.z;
    y.w = (o[3] - mu)*inv*lw.w + lb.w;
    ((float4*)(out + row*Dd))[tid] = y;
}

extern "C" void kernel_launch(void* const* d_in, const int* in_sizes, int n_in,
                              void* d_out, int out_size, void* d_ws, size_t ws_size,
                              hipStream_t stream)
{
    const float* X     = (const float*)d_in[0];
    const float* posW  = (const float*)d_in[1];
    const float* posB  = (const float*)d_in[2];
    const float* pbias = (const float*)d_in[3];
    const float* spos  = (const float*)d_in[4];
    const float* lsc   = (const float*)d_in[5];
    const float* qW    = (const float*)d_in[6];
    const float* kW    = (const float*)d_in[7];
    const float* vW    = (const float*)d_in[8];
    const float* gates = (const float*)d_in[9];
    const float* rwp   = (const float*)d_in[10];
    const float* lnw   = (const float*)d_in[11];
    const float* lnb   = (const float*)d_in[12];

    char* ws = (char*)d_ws;
    size_t off = 0;
    float* w_infl = (float*)(ws + off); off += (size_t)Bb*Ss*Nn*4;
    bf16*  Xb     = (bf16*) (ws + off); off += (size_t)Bb*Ss*Dd*2;
    bf16*  Wt     = (bf16*) (ws + off); off += (size_t)3*Dd*Dd*2;
    bf16*  WpT    = (bf16*) (ws + off); off += (size_t)Ee*Dd*2;
    bf16*  Q      = (bf16*) (ws + off); off += (size_t)Bb*Ss*Dd*2;
    bf16*  Kmat   = (bf16*) (ws + off); off += (size_t)Bb*Ss*Dd*2;
    bf16*  V      = (bf16*) (ws + off); off += (size_t)Bb*Ss*Dd*2;
    bf16*  Vt     = (bf16*) (ws + off); off += (size_t)Bb*Dd*Ss*2;
    float* qk     = (float*)(ws + off); off += (size_t)Bb*Ss*Ss*4;
    bf16*  Aav    = (bf16*) (ws + off); off += (size_t)Bb*Ss*Ss*2;
    float* comb   = (float*)(ws + off); off += (size_t)Bb*Ss*Dd*4;
    (void)Kmat; (void)ws_size;

    dim3 blk(256);
    // 1) all weight transposes + casts in one launch
    k_prep<<<dim3(16,16,4), blk, 0, stream>>>(qW, kW, vW, posW, Wt, WpT);
    // 2) X -> bf16
    k_cast<<<dim3(Bb*Ss*Dd/1024), blk, 0, stream>>>(X, Xb);
    // 3) MFMA pos GEMM + fused influence
    k_pos_gemm<<<dim3(Bb*Ss/64), blk, 0, stream>>>(Xb, WpT, posB, pbias, spos, lsc, w_infl);
    // 4) Q,K,V = Xb @ W^T   (64x128 tiles, 768 blocks)
    k_gemm64<1><<<dim3(8,32,3), blk, 0, stream>>>(Xb, Wt, (void*)Q,
        Bb*Ss, Dd, Dd, 0L, (long)Dd*Dd, (long)Bb*Ss*Dd, 1.f, 0);
    // 5) V^T per batch
    k_transpose_bf<<<dim3(16,16,2), blk, 0, stream>>>(V, Vt, Ss, Dd, (long)Ss*Dd, (long)Dd*Ss);
    // 6) qk = Q @ K^T / 32, lower-tri tiles only (144 active blocks)
    k_gemm64<0><<<dim3(8,16,2), blk, 0, stream>>>(Q, Kmat, (void*)qk,
        Ss, Ss, Dd, (long)Ss*Dd, (long)Ss*Dd, (long)Ss*Ss, 0.03125f, 1);
    // 7) softmax + gated average, 4 rows/block (512 blocks)
    k_softmax_avg4<<<dim3(Ss/4, Bb), blk, 0, stream>>>(qk, w_infl, gates, Aav);
    // 8) combined = A_avg @ V, K bounded by diagonal (256 blocks)
    k_gemm64<0><<<dim3(8,16,2), blk, 0, stream>>>(Aav, Vt, (void*)comb,
        Ss, Dd, Ss, (long)Ss*Ss, (long)Dd*Ss, (long)Ss*Dd, 1.f, 2);
    // 9) residual + LayerNorm
    k_epilogue<<<dim3(Bb*Ss), blk, 0, stream>>>(comb, X, lnw, lnb, rwp, (float*)d_out);
}

// Round 6
// 180.043 us; speedup vs baseline: 1.5824x; 1.1775x over previous
//
#include <hip/hip_runtime.h>
#include <hip/hip_bf16.h>
#include <hip/hip_fp16.h>

using bf16 = __hip_bfloat16;
typedef __attribute__((ext_vector_type(8))) short short8;
typedef __attribute__((ext_vector_type(4))) float f32x4;

static constexpr int Bb = 2, Ss = 1024, Dd = 1024, Ee = 64, Nn = 16;

struct Params {
    const float *X, *posW, *posB, *pbias, *spos, *lsc, *qW, *kW, *vW, *gates, *rwp, *lnw, *lnb;
    bf16 *Xb, *Wt, *WpT, *QKV, *Vt, *Aav;
    __half *wh;
    float *qk0, *qk1, *cb0, *cb1, *out;
};

__device__ __forceinline__ unsigned short f2bfr(float f) {
    __hip_bfloat16 h = __float2bfloat16(f);
    return *reinterpret_cast<unsigned short*>(&h);
}

#define GL_LDS(gp, lp) __builtin_amdgcn_global_load_lds( \
    (const __attribute__((address_space(1))) void*)(gp), \
    (__attribute__((address_space(3))) void*)(lp), 16, 0, 0)

// ---------- f32 -> bf16 transpose of a 64x64 tile ----------
__device__ __forceinline__ void do_transpose_f2b(
    const float* __restrict__ in, bf16* __restrict__ out,
    int R, int C, int bx, int by, char* sm)
{
    float (*tile)[65] = (float(*)[65])sm;
    int tx = threadIdx.x & 63, ty = threadIdx.x >> 6;
    int r0 = by * 64, c0 = bx * 64;
    #pragma unroll
    for (int i = 0; i < 16; ++i)
        tile[ty + i*4][tx] = in[(long)(r0 + ty + i*4)*C + c0 + tx];
    __syncthreads();
    #pragma unroll
    for (int i = 0; i < 16; ++i)
        out[(long)(c0 + ty + i*4)*R + r0 + tx] = __float2bfloat16(tile[tx][ty + i*4]);
    __syncthreads();
}

// ---------- bf16 transpose of a 64x64 tile ----------
__device__ __forceinline__ void do_transpose_bf(
    const bf16* __restrict__ in, bf16* __restrict__ out,
    int R, int C, int bx, int by, char* sm)
{
    bf16 (*tile)[65] = (bf16(*)[65])sm;
    int tx = threadIdx.x & 63, ty = threadIdx.x >> 6;
    int r0 = by * 64, c0 = bx * 64;
    #pragma unroll
    for (int i = 0; i < 16; ++i)
        tile[ty + i*4][tx] = in[(long)(r0 + ty + i*4)*C + c0 + tx];
    __syncthreads();
    #pragma unroll
    for (int i = 0; i < 16; ++i)
        out[(long)(c0 + ty + i*4)*R + r0 + tx] = tile[tx][ty + i*4];
    __syncthreads();
}

// ---------- 64x128 MFMA GEMM tile: C = scale * A @ Bt^T over k in [kBeg,kEnd) ----------
// A, Bt row-major with leading dim 1024 (true for every call site here).
template<int OUT_BF16>
__device__ __forceinline__ void do_gemm64(
    const bf16* __restrict__ Ab, const bf16* __restrict__ Bw, void* __restrict__ Cv,
    int Nc, int m0, int n0, int kBeg, int kEnd, float scale, char* sm)
{
    short* lA = (short*)sm;            // 64*32*2  = 4 KB
    short* lB = (short*)(sm + 4096);   // 128*32*2 = 8 KB
    int tid = threadIdx.x, wid = tid >> 6, lane = tid & 63;
    int wn = wid * 32, r16 = lane & 15, quad = lane >> 4;

    f32x4 acc[4][2];
    #pragma unroll
    for (int i = 0; i < 4; ++i)
        #pragma unroll
        for (int j = 0; j < 2; ++j)
            #pragma unroll
            for (int c = 0; c < 4; ++c) acc[i][j][c] = 0.f;

    int ra  = tid >> 2, ka  = (tid & 3) * 8;
    int c1  = tid + 256, rb1 = c1 >> 2, kb1 = (c1 & 3) * 8;
    const short* Ag = (const short*)Ab;
    const short* Bg = (const short*)Bw;

    for (int k0 = kBeg; k0 < kEnd; k0 += 32) {
        __syncthreads();
        GL_LDS(Ag + (long)(m0+ra)*1024 + k0 + ka,  lA + tid*8);
        GL_LDS(Bg + (long)(n0+ra)*1024 + k0 + ka,  lB + tid*8);
        GL_LDS(Bg + (long)(n0+rb1)*1024 + k0 + kb1, lB + c1*8);
        __syncthreads();

        short8 af[4], bfv[2];
        #pragma unroll
        for (int i = 0; i < 4; ++i) af[i]  = *(const short8*)(lA + (i*16 + r16)*32 + quad*8);
        #pragma unroll
        for (int j = 0; j < 2; ++j) bfv[j] = *(const short8*)(lB + (wn + j*16 + r16)*32 + quad*8);
        #pragma unroll
        for (int i = 0; i < 4; ++i)
            #pragma unroll
            for (int j = 0; j < 2; ++j)
                acc[i][j] = __builtin_amdgcn_mfma_f32_16x16x32_bf16(af[i], bfv[j], acc[i][j], 0, 0, 0);
    }

    if (OUT_BF16) {
        bf16* C = (bf16*)Cv;
        #pragma unroll
        for (int i = 0; i < 4; ++i)
            #pragma unroll
            for (int j = 0; j < 2; ++j)
                #pragma unroll
                for (int rr = 0; rr < 4; ++rr)
                    C[(long)(m0 + i*16 + quad*4 + rr)*Nc + n0 + wn + j*16 + r16] =
                        __float2bfloat16(acc[i][j][rr] * scale);
    } else {
        float* C = (float*)Cv;
        #pragma unroll
        for (int i = 0; i < 4; ++i)
            #pragma unroll
            for (int j = 0; j < 2; ++j)
                #pragma unroll
                for (int rr = 0; rr < 4; ++rr)
                    C[(long)(m0 + i*16 + quad*4 + rr)*Nc + n0 + wn + j*16 + r16] =
                        acc[i][j][rr] * scale;
    }
}

// ---------- pos GEMM (64 rows) + tanh/bias + splat influence -> wh (half) ----------
__device__ __forceinline__ void do_pos(const Params& p, int m0, char* sm)
{
    short* lA = (short*)sm;                         // 4 KB
    short* lB = (short*)(sm + 4096);                // 4 KB
    float (*P)[65]  = (float(*)[65])(sm + 8192);    // 16.64 KB
    float (*sp)[65] = (float(*)[65])(sm + 8192 + 64*65*4); // 4.16 KB

    int tid = threadIdx.x, wid = tid >> 6, lane = tid & 63;
    int r16 = lane & 15, quad = lane >> 4;

    for (int idx = tid; idx < 16*64; idx += 256)
        sp[idx >> 6][idx & 63] = p.spos[idx];

    f32x4 acc[4];
    #pragma unroll
    for (int j = 0; j < 4; ++j)
        #pragma unroll
        for (int c = 0; c < 4; ++c) acc[j][c] = 0.f;

    int ra = tid >> 2, ka = (tid & 3) * 8;
    const short* Ag = (const short*)p.Xb;
    const short* Bg = (const short*)p.WpT;

    for (int k0 = 0; k0 < Dd; k0 += 32) {
        __syncthreads();
        GL_LDS(Ag + (long)(m0+ra)*1024 + k0 + ka, lA + tid*8);
        GL_LDS(Bg + (long)ra*1024 + k0 + ka,      lB + tid*8);
        __syncthreads();

        short8 af = *(const short8*)(lA + (wid*16 + r16)*32 + quad*8);
        #pragma unroll
        for (int j = 0; j < 4; ++j) {
            short8 bfv = *(const short8*)(lB + (j*16 + r16)*32 + quad*8);
            acc[j] = __builtin_amdgcn_mfma_f32_16x16x32_bf16(af, bfv, acc[j], 0, 0, 0);
        }
    }

    #pragma unroll
    for (int j = 0; j < 4; ++j)
        #pragma unroll
        for (int rr = 0; rr < 4; ++rr) {
            int rl  = wid*16 + quad*4 + rr;
            int col = j*16 + r16;
            int srow = (m0 + rl) & (Ss - 1);
            P[rl][col] = tanhf(acc[j][rr] + p.posB[col]) + p.pbias[srow*Ee + col];
        }
    __syncthreads();

    int n  = tid & 15;
    int rb = (tid >> 4) * 4;
    float sc = __expf(p.lsc[n]);
    sc = fminf(fmaxf(sc, 0.3f), 2.0f);
    float inv2 = -0.5f / (sc * sc);
    #pragma unroll
    for (int rr = 0; rr < 4; ++rr) {
        int row = rb + rr;
        float d2 = 0.f;
        #pragma unroll 16
        for (int e = 0; e < 64; ++e) {
            float df = P[row][e] - sp[n][e];
            d2 += df * df;
        }
        float infl = fmaxf(__expf(d2 * inv2), 0.01f);
        p.wh[(long)(m0 + row)*Nn + n] = __float2half(infl);
    }
}

// ========== K1: weight transposes + posW^T + X cast ==========
__global__ __launch_bounds__(256) void k_prep(Params p)
{
    __shared__ __align__(16) char sm[64*65*4];
    int z = blockIdx.z;
    if (z < 3) {
        const float* w = (z == 0) ? p.qW : (z == 1) ? p.kW : p.vW;
        do_transpose_f2b(w, p.Wt + (long)z*Dd*Dd, Dd, Dd, blockIdx.x, blockIdx.y, sm);
    } else if (blockIdx.x == 0) {
        do_transpose_f2b(p.posW, p.WpT, Dd, Ee, 0, blockIdx.y, sm);
    } else {
        // X cast on the 240 idle blocks: 524288 float4s, grid-stride
        int job = blockIdx.y * 15 + (blockIdx.x - 1);     // 0..239
        const float4* src = (const float4*)p.X;
        ushort4* dst = (ushort4*)p.Xb;
        for (int idx = job*256 + (int)threadIdx.x; idx < Bb*Ss*Dd/4; idx += 240*256) {
            float4 v = src[idx];
            ushort4 y;
            y.x = f2bfr(v.x); y.y = f2bfr(v.y); y.z = f2bfr(v.z); y.w = f2bfr(v.w);
            dst[idx] = y;
        }
    }
}

// ========== K2: QKV GEMM (768 jobs) + pos GEMM/influence (32 jobs) ==========
__global__ __launch_bounds__(256) void k_qkv_pos(Params p)
{
    __shared__ __align__(16) char sm[8192 + 64*65*4 + 16*65*4];
    int job = blockIdx.x;
    if (job < 768) {
        int z = job >> 8, t = job & 255;
        int bm = t >> 3, bn = t & 7;
        do_gemm64<1>(p.Xb, p.Wt + (long)z*Dd*Dd, p.QKV + (long)z*2048*1024,
                     Dd, bm*64, bn*128, 0, Dd, 1.f, sm);
    } else {
        do_pos(p, (job - 768)*64, sm);
    }
}

// ========== K3: qk split-K (288 jobs) + V transpose (256 jobs x 2 tiles) ==========
__global__ __launch_bounds__(256) void k_qkt_vt(Params p)
{
    __shared__ __align__(16) char sm[12288];
    int job = blockIdx.x;
    if (job < 288) {
        int pairIdx = job >> 1, h = job & 1;
        int b = pairIdx / 72, t = pairIdx % 72;
        int acc = 0, bm = 0, bn = 0;
        #pragma unroll
        for (int u = 0; u < 16; ++u) {
            int c = (u >> 1) + 1;
            if (t < acc + c) { bm = u; bn = t - acc; break; }
            acc += c;
        }
        const bf16* Qb = p.QKV + (long)b*Ss*Dd;
        const bf16* Kb = p.QKV + (long)2048*1024 + (long)b*Ss*Dd;
        float* dst = (h ? p.qk1 : p.qk0) + (long)b*Ss*Ss;
        do_gemm64<0>(Qb, Kb, dst, Ss, bm*64, bn*128, h*512, h*512 + 512, 0.03125f, sm);
    } else {
        int j2 = job - 288;                      // 0..255
        int b = j2 >> 7, tt = j2 & 127;
        int r = tt >> 3, cp = (tt & 7) * 2;
        const bf16* Vb = p.QKV + (long)2*2048*1024 + (long)b*Ss*Dd;
        bf16* Vtb = p.Vt + (long)b*Dd*Ss;
        do_transpose_bf(Vb, Vtb, Ss, Dd, cp,     r, sm);
        do_transpose_bf(Vb, Vtb, Ss, Dd, cp + 1, r, sm);
    }
}

// ========== K4: softmax + gated average, 4 rows/block (1 wave/row) ==========
__global__ __launch_bounds__(256) void k_softmax(Params p)
{
    __shared__ __align__(16) char sm[36864 + 256];
    __half2 (*wt)[9] = (__half2(*)[9])sm;
    float (*wi4)[16] = (float(*)[16])(sm + 36864);

    int base = blockIdx.x * 4, b = blockIdx.y;
    int tid = threadIdx.x, wid = tid >> 6, lane = tid & 63;
    int imax = base + 3;

    const __half*  whb  = p.wh + (long)b*Ss*Nn;
    const __half2* whb2 = (const __half2*)whb;

    for (int j = tid; j <= imax; j += 256) {
        #pragma unroll
        for (int h = 0; h < 8; ++h)
            wt[j][h] = whb2[j*8 + h];
    }
    if (tid < 64) wi4[tid >> 4][tid & 15] =
        __half2float(whb[(long)(base + (tid >> 4))*16 + (tid & 15)]);
    __syncthreads();

    int i = base + wid;
    const float* q0 = p.qk0 + ((long)b*Ss + i)*Ss;
    const float* q1 = p.qk1 + ((long)b*Ss + i)*Ss;
    bf16* arow      = p.Aav + ((long)b*Ss + i)*Ss;

    float wiR[16], m[16], l[16];
    #pragma unroll
    for (int n = 0; n < 16; ++n) { wiR[n] = wi4[wid][n]; m[n] = -1e30f; l[n] = 0.f; }

    for (int j = lane; j <= i; j += 64) {
        float q = q0[j] + q1[j];
        #pragma unroll
        for (int h = 0; h < 8; ++h) {
            float2 f = __half22float2(wt[j][h]);
            m[2*h]     = fmaxf(m[2*h],     wiR[2*h]     * f.x * q);
            m[2*h + 1] = fmaxf(m[2*h + 1], wiR[2*h + 1] * f.y * q);
        }
    }
    #pragma unroll
    for (int n = 0; n < 16; ++n)
        #pragma unroll
        for (int off = 32; off > 0; off >>= 1)
            m[n] = fmaxf(m[n], __shfl_xor(m[n], off));

    for (int j = lane; j <= i; j += 64) {
        float q = q0[j] + q1[j];
        #pragma unroll
        for (int h = 0; h < 8; ++h) {
            float2 f = __half22float2(wt[j][h]);
            l[2*h]     += __expf(wiR[2*h]     * f.x * q - m[2*h]);
            l[2*h + 1] += __expf(wiR[2*h + 1] * f.y * q - m[2*h + 1]);
        }
    }
    #pragma unroll
    for (int n = 0; n < 16; ++n)
        #pragma unroll
        for (int off = 32; off > 0; off >>= 1)
            l[n] += __shfl_xor(l[n], off);

    float coef[16];
    #pragma unroll
    for (int n = 0; n < 16; ++n) {
        float g  = p.gates[n];
        float sg = 1.f / (1.f + __expf(-g));
        coef[n]  = sg / (16.f * l[n]);
    }

    for (int j = lane; j < Ss; j += 64) {
        float a = 0.f;
        if (j <= i) {
            float q = q0[j] + q1[j];
            #pragma unroll
            for (int h = 0; h < 8; ++h) {
                float2 f = __half22float2(wt[j][h]);
                a += coef[2*h]     * __expf(wiR[2*h]     * f.x * q - m[2*h]);
                a += coef[2*h + 1] * __expf(wiR[2*h + 1] * f.y * q - m[2*h + 1]);
            }
        }
        arow[j] = __float2bfloat16(a);
    }
}

// ========== K5: AV GEMM split-K (384 jobs) ==========
__global__ __launch_bounds__(256) void k_av(Params p)
{
    __shared__ __align__(16) char sm[12288];
    int job = blockIdx.x;
    int b, bm, bn, kBeg, kEnd;
    if (job < 256) {
        b = job >> 7; int t = job & 127; bm = t >> 3; bn = t & 7;
        kBeg = 0; kEnd = bm*64 + 64; if (kEnd > 512) kEnd = 512;
    } else {
        int j = job - 256;
        b = j >> 6; int t = j & 63; bm = 8 + (t >> 3); bn = t & 7;
        kBeg = 512; kEnd = bm*64 + 64;
    }
    const bf16* Ab = p.Aav + (long)b*Ss*Ss;
    const bf16* Bw = p.Vt + (long)b*Dd*Ss;
    float* dst = (job < 256 ? p.cb0 : p.cb1) + (long)b*Ss*Dd;
    do_gemm64<0>(Ab, Bw, dst, Dd, bm*64, bn*128, kBeg, kEnd, 1.f, sm);
}

// ========== K6: residual + LayerNorm ==========
__global__ __launch_bounds__(256) void k_epilogue(Params p)
{
    __shared__ float rs[4], rq[4];
    long row = blockIdx.x;
    int tid = threadIdx.x, wid = tid >> 6, lane = tid & 63;
    float rw = 1.f / (1.f + __expf(-p.rwp[0]));

    float4 c0 = ((const float4*)(p.cb0 + row*Dd))[tid];
    int s = (int)(row & (Ss - 1));
    float4 c1 = make_float4(0.f, 0.f, 0.f, 0.f);
    if (s >= 512) c1 = ((const float4*)(p.cb1 + row*Dd))[tid];
    float4 xv = ((const float4*)(p.X + row*Dd))[tid];

    float o[4];
    o[0] = rw * xv.x + (1.f - rw) * (c0.x + c1.x);
    o[1] = rw * xv.y + (1.f - rw) * (c0.y + c1.y);
    o[2] = rw * xv.z + (1.f - rw) * (c0.z + c1.z);
    o[3] = rw * xv.w + (1.f - rw) * (c0.w + c1.w);

    float sm1 = o[0] + o[1] + o[2] + o[3];
    float sq  = o[0]*o[0] + o[1]*o[1] + o[2]*o[2] + o[3]*o[3];
    #pragma unroll
    for (int off = 32; off > 0; off >>= 1) { sm1 += __shfl_xor(sm1, off); sq += __shfl_xor(sq, off); }
    if (lane == 0) { rs[wid] = sm1; rq[wid] = sq; }
    __syncthreads();
    sm1 = rs[0] + rs[1] + rs[2] + rs[3];
    sq  = rq[0] + rq[1] + rq[2] + rq[3];
    float mu  = sm1 * (1.f/1024.f);
    float var = sq * (1.f/1024.f) - mu*mu;
    float inv = rsqrtf(var + 1e-5f);

    float4 lw = ((const float4*)p.lnw)[tid];
    float4 lb = ((const float4*)p.lnb)[tid];
    float4 y;
    y.x = (o[0] - mu)*inv*lw.x + lb.x;
    y.y = (o[1] - mu)*inv*lw.y + lb.y;
    y.z = (o[2] - mu)*inv*lw.z + lb.z;
    y.w = (o[3] - mu)*inv*lw.w + lb.w;
    ((float4*)(p.out + row*Dd))[tid] = y;
}

extern "C" void kernel_launch(void* const* d_in, const int* in_sizes, int n_in,
                              void* d_out, int out_size, void* d_ws, size_t ws_size,
                              hipStream_t stream)
{
    Params prm;
    prm.X     = (const float*)d_in[0];
    prm.posW  = (const float*)d_in[1];
    prm.posB  = (const float*)d_in[2];
    prm.pbias = (const float*)d_in[3];
    prm.spos  = (const float*)d_in[4];
    prm.lsc   = (const float*)d_in[5];
    prm.qW    = (const float*)d_in[6];
    prm.kW    = (const float*)d_in[7];
    prm.vW    = (const float*)d_in[8];
    prm.gates = (const float*)d_in[9];
    prm.rwp   = (const float*)d_in[10];
    prm.lnw   = (const float*)d_in[11];
    prm.lnb   = (const float*)d_in[12];

    char* ws = (char*)d_ws;
    size_t off = 0;
    prm.Xb  = (bf16*)(ws + off);   off += (size_t)Bb*Ss*Dd*2;
    prm.Wt  = (bf16*)(ws + off);   off += (size_t)3*Dd*Dd*2;
    prm.WpT = (bf16*)(ws + off);   off += (size_t)Ee*Dd*2;
    prm.QKV = (bf16*)(ws + off);   off += (size_t)3*Bb*Ss*Dd*2;
    prm.Vt  = (bf16*)(ws + off);   off += (size_t)Bb*Dd*Ss*2;
    prm.Aav = (bf16*)(ws + off);   off += (size_t)Bb*Ss*Ss*2;
    prm.wh  = (__half*)(ws + off); off += (size_t)Bb*Ss*Nn*2;
    prm.qk0 = (float*)(ws + off);  off += (size_t)Bb*Ss*Ss*4;
    prm.qk1 = (float*)(ws + off);  off += (size_t)Bb*Ss*Ss*4;
    prm.cb0 = (float*)(ws + off);  off += (size_t)Bb*Ss*Dd*4;
    prm.cb1 = (float*)(ws + off);  off += (size_t)Bb*Ss*Dd*4;
    prm.out = (float*)d_out;
    (void)ws_size;

    k_prep    <<<dim3(16,16,4), 256, 0, stream>>>(prm);
    k_qkv_pos <<<800,            256, 0, stream>>>(prm);
    k_qkt_vt  <<<544,            256, 0, stream>>>(prm);
    k_softmax <<<dim3(256, 2),   256, 0, stream>>>(prm);
    k_av      <<<384,            256, 0, stream>>>(prm);
    k_epilogue<<<2048,           256, 0, stream>>>(prm);
}

// Round 7
// 172.661 us; speedup vs baseline: 1.6501x; 1.0428x over previous
//
#include <hip/hip_runtime.h>
#include <hip/hip_bf16.h>
#include <hip/hip_fp16.h>

using bf16 = __hip_bfloat16;
typedef __attribute__((ext_vector_type(8))) short short8;
typedef __attribute__((ext_vector_type(4))) float f32x4;

static constexpr int Bb = 2, Ss = 1024, Dd = 1024, Ee = 64, Nn = 16;

struct Params {
    const float *X, *posW, *posB, *pbias, *spos, *lsc, *qW, *kW, *vW, *gates, *rwp, *lnw, *lnb;
    bf16 *Xb, *Wt, *WpT, *QKV, *Vt, *Aav;
    __half *wh;
    float *qk0, *qk1, *cb0, *cb1, *out;
};

__device__ __forceinline__ unsigned short f2bfr(float f) {
    __hip_bfloat16 h = __float2bfloat16(f);
    return *reinterpret_cast<unsigned short*>(&h);
}

#define GL_LDS(gp, lp) __builtin_amdgcn_global_load_lds( \
    (const __attribute__((address_space(1))) void*)(gp), \
    (__attribute__((address_space(3))) void*)(lp), 16, 0, 0)

// ---------- f32 -> bf16 transpose of a 64x64 tile ----------
__device__ __forceinline__ void do_transpose_f2b(
    const float* __restrict__ in, bf16* __restrict__ out,
    int R, int C, int bx, int by, char* sm)
{
    float (*tile)[65] = (float(*)[65])sm;
    int tx = threadIdx.x & 63, ty = threadIdx.x >> 6;
    int r0 = by * 64, c0 = bx * 64;
    #pragma unroll
    for (int i = 0; i < 16; ++i)
        tile[ty + i*4][tx] = in[(long)(r0 + ty + i*4)*C + c0 + tx];
    __syncthreads();
    #pragma unroll
    for (int i = 0; i < 16; ++i)
        out[(long)(c0 + ty + i*4)*R + r0 + tx] = __float2bfloat16(tile[tx][ty + i*4]);
    __syncthreads();
}

// ---------- bf16 transpose of a 64x64 tile ----------
__device__ __forceinline__ void do_transpose_bf(
    const bf16* __restrict__ in, bf16* __restrict__ out,
    int R, int C, int bx, int by, char* sm)
{
    bf16 (*tile)[65] = (bf16(*)[65])sm;
    int tx = threadIdx.x & 63, ty = threadIdx.x >> 6;
    int r0 = by * 64, c0 = bx * 64;
    #pragma unroll
    for (int i = 0; i < 16; ++i)
        tile[ty + i*4][tx] = in[(long)(r0 + ty + i*4)*C + c0 + tx];
    __syncthreads();
    #pragma unroll
    for (int i = 0; i < 16; ++i)
        out[(long)(c0 + ty + i*4)*R + r0 + tx] = tile[tx][ty + i*4];
    __syncthreads();
}

// ---------- 64x128 MFMA GEMM tile, BK=64, XOR-swizzled LDS ----------
// C = scale * A @ Bt^T over k in [kBeg,kEnd); A,Bt row-major, ld = 1024.
// 16B chunk (row, kc) of the tile lives at LDS chunk row*8 + (kc ^ (row&7)):
// ds_read bank-group = kc ^ (r&7) -> 8 distinct groups, 2-way only (free).
template<int OUT_BF16>
__device__ __forceinline__ void do_gemm64(
    const bf16* __restrict__ Ab, const bf16* __restrict__ Bw, void* __restrict__ Cv,
    int Nc, int m0, int n0, int kBeg, int kEnd, float scale, char* sm)
{
    short* lA = (short*)sm;            // 64*64*2  = 8 KB
    short* lB = (short*)(sm + 8192);   // 128*64*2 = 16 KB
    int tid = threadIdx.x, wid = tid >> 6, lane = tid & 63;
    int wn = wid * 32, r16 = lane & 15, quad = lane >> 4;

    f32x4 acc[4][2];
    #pragma unroll
    for (int i = 0; i < 4; ++i)
        #pragma unroll
        for (int j = 0; j < 2; ++j)
            #pragma unroll
            for (int c = 0; c < 4; ++c) acc[i][j][c] = 0.f;

    const short* Ag = (const short*)Ab;
    const short* Bg = (const short*)Bw;

    // precompute per-thread staging (chunk c -> row = c>>3, global k-chunk = (c&7)^(row&7))
    int arow[2], akg[2], brow[4], bkg[4];
    #pragma unroll
    for (int j = 0; j < 2; ++j) {
        int c = tid + j*256; arow[j] = c >> 3; akg[j] = (c & 7) ^ (arow[j] & 7);
    }
    #pragma unroll
    for (int j = 0; j < 4; ++j) {
        int c = tid + j*256; brow[j] = c >> 3; bkg[j] = (c & 7) ^ (brow[j] & 7);
    }

    for (int k0 = kBeg; k0 < kEnd; k0 += 64) {
        __syncthreads();
        #pragma unroll
        for (int j = 0; j < 2; ++j)
            GL_LDS(Ag + (long)(m0 + arow[j])*1024 + k0 + akg[j]*8, lA + (tid + j*256)*8);
        #pragma unroll
        for (int j = 0; j < 4; ++j)
            GL_LDS(Bg + (long)(n0 + brow[j])*1024 + k0 + bkg[j]*8, lB + (tid + j*256)*8);
        __syncthreads();

        #pragma unroll
        for (int kk = 0; kk < 2; ++kk) {
            int kc = kk*4 + quad;
            short8 af[4], bfv[2];
            #pragma unroll
            for (int i = 0; i < 4; ++i) {
                int r = i*16 + r16;
                af[i] = *(const short8*)(lA + r*64 + (kc ^ (r & 7))*8);
            }
            #pragma unroll
            for (int j = 0; j < 2; ++j) {
                int r = wn + j*16 + r16;
                bfv[j] = *(const short8*)(lB + r*64 + (kc ^ (r & 7))*8);
            }
            #pragma unroll
            for (int i = 0; i < 4; ++i)
                #pragma unroll
                for (int j = 0; j < 2; ++j)
                    acc[i][j] = __builtin_amdgcn_mfma_f32_16x16x32_bf16(af[i], bfv[j], acc[i][j], 0, 0, 0);
        }
    }

    if (OUT_BF16) {
        bf16* C = (bf16*)Cv;
        #pragma unroll
        for (int i = 0; i < 4; ++i)
            #pragma unroll
            for (int j = 0; j < 2; ++j)
                #pragma unroll
                for (int rr = 0; rr < 4; ++rr)
                    C[(long)(m0 + i*16 + quad*4 + rr)*Nc + n0 + wn + j*16 + r16] =
                        __float2bfloat16(acc[i][j][rr] * scale);
    } else {
        float* C = (float*)Cv;
        #pragma unroll
        for (int i = 0; i < 4; ++i)
            #pragma unroll
            for (int j = 0; j < 2; ++j)
                #pragma unroll
                for (int rr = 0; rr < 4; ++rr)
                    C[(long)(m0 + i*16 + quad*4 + rr)*Nc + n0 + wn + j*16 + r16] =
                        acc[i][j][rr] * scale;
    }
}

// ---------- pos GEMM (64 rows) + tanh/bias + splat influence -> wh (half) ----------
__device__ __forceinline__ void do_pos(const Params& p, int m0, char* sm)
{
    short* lA = (short*)sm;                         // 4 KB
    short* lB = (short*)(sm + 4096);                // 4 KB
    float (*P)[65]  = (float(*)[65])(sm + 8192);    // 16.64 KB
    float (*sp)[65] = (float(*)[65])(sm + 8192 + 64*65*4); // 4.16 KB

    int tid = threadIdx.x, wid = tid >> 6, lane = tid & 63;
    int r16 = lane & 15, quad = lane >> 4;

    for (int idx = tid; idx < 16*64; idx += 256)
        sp[idx >> 6][idx & 63] = p.spos[idx];

    f32x4 acc[4];
    #pragma unroll
    for (int j = 0; j < 4; ++j)
        #pragma unroll
        for (int c = 0; c < 4; ++c) acc[j][c] = 0.f;

    int ra = tid >> 2, ka = (tid & 3) * 8;
    const short* Ag = (const short*)p.Xb;
    const short* Bg = (const short*)p.WpT;

    for (int k0 = 0; k0 < Dd; k0 += 32) {
        __syncthreads();
        GL_LDS(Ag + (long)(m0+ra)*1024 + k0 + ka, lA + tid*8);
        GL_LDS(Bg + (long)ra*1024 + k0 + ka,      lB + tid*8);
        __syncthreads();

        short8 af = *(const short8*)(lA + (wid*16 + r16)*32 + quad*8);
        #pragma unroll
        for (int j = 0; j < 4; ++j) {
            short8 bfv = *(const short8*)(lB + (j*16 + r16)*32 + quad*8);
            acc[j] = __builtin_amdgcn_mfma_f32_16x16x32_bf16(af, bfv, acc[j], 0, 0, 0);
        }
    }

    #pragma unroll
    for (int j = 0; j < 4; ++j)
        #pragma unroll
        for (int rr = 0; rr < 4; ++rr) {
            int rl  = wid*16 + quad*4 + rr;
            int col = j*16 + r16;
            int srow = (m0 + rl) & (Ss - 1);
            P[rl][col] = tanhf(acc[j][rr] + p.posB[col]) + p.pbias[srow*Ee + col];
        }
    __syncthreads();

    int n  = tid & 15;
    int rb = (tid >> 4) * 4;
    float sc = __expf(p.lsc[n]);
    sc = fminf(fmaxf(sc, 0.3f), 2.0f);
    float inv2 = -0.5f / (sc * sc);
    #pragma unroll
    for (int rr = 0; rr < 4; ++rr) {
        int row = rb + rr;
        float d2 = 0.f;
        #pragma unroll 16
        for (int e = 0; e < 64; ++e) {
            float df = P[row][e] - sp[n][e];
            d2 += df * df;
        }
        float infl = fmaxf(__expf(d2 * inv2), 0.01f);
        p.wh[(long)(m0 + row)*Nn + n] = __float2half(infl);
    }
}

// ========== K1: weight transposes + posW^T + X cast ==========
__global__ __launch_bounds__(256) void k_prep(Params p)
{
    __shared__ __align__(16) char sm[64*65*4];
    int z = blockIdx.z;
    if (z < 3) {
        const float* w = (z == 0) ? p.qW : (z == 1) ? p.kW : p.vW;
        do_transpose_f2b(w, p.Wt + (long)z*Dd*Dd, Dd, Dd, blockIdx.x, blockIdx.y, sm);
    } else if (blockIdx.x == 0) {
        do_transpose_f2b(p.posW, p.WpT, Dd, Ee, 0, blockIdx.y, sm);
    } else {
        // X cast on the 240 idle blocks: 524288 float4s, grid-stride
        int job = blockIdx.y * 15 + (blockIdx.x - 1);     // 0..239
        const float4* src = (const float4*)p.X;
        ushort4* dst = (ushort4*)p.Xb;
        for (int idx = job*256 + (int)threadIdx.x; idx < Bb*Ss*Dd/4; idx += 240*256) {
            float4 v = src[idx];
            ushort4 y;
            y.x = f2bfr(v.x); y.y = f2bfr(v.y); y.z = f2bfr(v.z); y.w = f2bfr(v.w);
            dst[idx] = y;
        }
    }
}

// ========== K2: QKV GEMM (768 jobs) + pos GEMM/influence (32 jobs) ==========
__global__ __launch_bounds__(256) void k_qkv_pos(Params p)
{
    __shared__ __align__(16) char sm[8192 + 64*65*4 + 16*65*4];   // 29.3 KB (pos needs most)
    int job = blockIdx.x;
    if (job < 768) {
        int z = job >> 8, t = job & 255;
        int bm = t >> 3, bn = t & 7;
        do_gemm64<1>(p.Xb, p.Wt + (long)z*Dd*Dd, p.QKV + (long)z*2048*1024,
                     Dd, bm*64, bn*128, 0, Dd, 1.f, sm);
    } else {
        do_pos(p, (job - 768)*64, sm);
    }
}

// ========== K3: qk split-K (288 jobs) + V transpose (256 jobs x 2 tiles) ==========
__global__ __launch_bounds__(256) void k_qkt_vt(Params p)
{
    __shared__ __align__(16) char sm[24576];
    int job = blockIdx.x;
    if (job < 288) {
        int pairIdx = job >> 1, h = job & 1;
        int b = pairIdx / 72, t = pairIdx % 72;
        int acc = 0, bm = 0, bn = 0;
        #pragma unroll
        for (int u = 0; u < 16; ++u) {
            int c = (u >> 1) + 1;
            if (t < acc + c) { bm = u; bn = t - acc; break; }
            acc += c;
        }
        const bf16* Qb = p.QKV + (long)b*Ss*Dd;
        const bf16* Kb = p.QKV + (long)2048*1024 + (long)b*Ss*Dd;
        float* dst = (h ? p.qk1 : p.qk0) + (long)b*Ss*Ss;
        do_gemm64<0>(Qb, Kb, dst, Ss, bm*64, bn*128, h*512, h*512 + 512, 0.03125f, sm);
    } else {
        int j2 = job - 288;                      // 0..255
        int b = j2 >> 7, tt = j2 & 127;
        int r = tt >> 3, cp = (tt & 7) * 2;
        const bf16* Vb = p.QKV + (long)2*2048*1024 + (long)b*Ss*Dd;
        bf16* Vtb = p.Vt + (long)b*Dd*Ss;
        do_transpose_bf(Vb, Vtb, Ss, Dd, cp,     r, sm);
        do_transpose_bf(Vb, Vtb, Ss, Dd, cp + 1, r, sm);
    }
}

// ========== K4: softmax + gated average, 4 rows/block (1 wave/row) ==========
__global__ __launch_bounds__(256) void k_softmax(Params p)
{
    __shared__ __align__(16) char sm[36864 + 256];
    __half2 (*wt)[9] = (__half2(*)[9])sm;
    float (*wi4)[16] = (float(*)[16])(sm + 36864);

    int base = blockIdx.x * 4, b = blockIdx.y;
    int tid = threadIdx.x, wid = tid >> 6, lane = tid & 63;
    int imax = base + 3;

    const __half*  whb  = p.wh + (long)b*Ss*Nn;
    const __half2* whb2 = (const __half2*)whb;

    for (int j = tid; j <= imax; j += 256) {
        #pragma unroll
        for (int h = 0; h < 8; ++h)
            wt[j][h] = whb2[j*8 + h];
    }
    if (tid < 64) wi4[tid >> 4][tid & 15] =
        __half2float(whb[(long)(base + (tid >> 4))*16 + (tid & 15)]);
    __syncthreads();

    int i = base + wid;
    const float* q0 = p.qk0 + ((long)b*Ss + i)*Ss;
    const float* q1 = p.qk1 + ((long)b*Ss + i)*Ss;
    bf16* arow      = p.Aav + ((long)b*Ss + i)*Ss;

    float wiR[16], m[16], l[16];
    #pragma unroll
    for (int n = 0; n < 16; ++n) { wiR[n] = wi4[wid][n]; m[n] = -1e30f; l[n] = 0.f; }

    for (int j = lane; j <= i; j += 64) {
        float q = q0[j] + q1[j];
        #pragma unroll
        for (int h = 0; h < 8; ++h) {
            float2 f = __half22float2(wt[j][h]);
            m[2*h]     = fmaxf(m[2*h],     wiR[2*h]     * f.x * q);
            m[2*h + 1] = fmaxf(m[2*h + 1], wiR[2*h + 1] * f.y * q);
        }
    }
    #pragma unroll
    for (int n = 0; n < 16; ++n)
        #pragma unroll
        for (int off = 32; off > 0; off >>= 1)
            m[n] = fmaxf(m[n], __shfl_xor(m[n], off));

    for (int j = lane; j <= i; j += 64) {
        float q = q0[j] + q1[j];
        #pragma unroll
        for (int h = 0; h < 8; ++h) {
            float2 f = __half22float2(wt[j][h]);
            l[2*h]     += __expf(wiR[2*h]     * f.x * q - m[2*h]);
            l[2*h + 1] += __expf(wiR[2*h + 1] * f.y * q - m[2*h + 1]);
        }
    }
    #pragma unroll
    for (int n = 0; n < 16; ++n)
        #pragma unroll
        for (int off = 32; off > 0; off >>= 1)
            l[n] += __shfl_xor(l[n], off);

    float coef[16];
    #pragma unroll
    for (int n = 0; n < 16; ++n) {
        float g  = p.gates[n];
        float sg = 1.f / (1.f + __expf(-g));
        coef[n]  = sg / (16.f * l[n]);
    }

    for (int j = lane; j < Ss; j += 64) {
        float a = 0.f;
        if (j <= i) {
            float q = q0[j] + q1[j];
            #pragma unroll
            for (int h = 0; h < 8; ++h) {
                float2 f = __half22float2(wt[j][h]);
                a += coef[2*h]     * __expf(wiR[2*h]     * f.x * q - m[2*h]);
                a += coef[2*h + 1] * __expf(wiR[2*h + 1] * f.y * q - m[2*h + 1]);
            }
        }
        arow[j] = __float2bfloat16(a);
    }
}

// ========== K5: AV GEMM split-K (384 jobs) ==========
__global__ __launch_bounds__(256) void k_av(Params p)
{
    __shared__ __align__(16) char sm[24576];
    int job = blockIdx.x;
    int b, bm, bn, kBeg, kEnd;
    if (job < 256) {
        b = job >> 7; int t = job & 127; bm = t >> 3; bn = t & 7;
        kBeg = 0; kEnd = bm*64 + 64; if (kEnd > 512) kEnd = 512;
    } else {
        int j = job - 256;
        b = j >> 6; int t = j & 63; bm = 8 + (t >> 3); bn = t & 7;
        kBeg = 512; kEnd = bm*64 + 64;
    }
    const bf16* Ab = p.Aav + (long)b*Ss*Ss;
    const bf16* Bw = p.Vt + (long)b*Dd*Ss;
    float* dst = (job < 256 ? p.cb0 : p.cb1) + (long)b*Ss*Dd;
    do_gemm64<0>(Ab, Bw, dst, Dd, bm*64, bn*128, kBeg, kEnd, 1.f, sm);
}

// ========== K6: residual + LayerNorm ==========
__global__ __launch_bounds__(256) void k_epilogue(Params p)
{
    __shared__ float rs[4], rq[4];
    long row = blockIdx.x;
    int tid = threadIdx.x, wid = tid >> 6, lane = tid & 63;
    float rw = 1.f / (1.f + __expf(-p.rwp[0]));

    float4 c0 = ((const float4*)(p.cb0 + row*Dd))[tid];
    int s = (int)(row & (Ss - 1));
    float4 c1 = make_float4(0.f, 0.f, 0.f, 0.f);
    if (s >= 512) c1 = ((const float4*)(p.cb1 + row*Dd))[tid];
    float4 xv = ((const float4*)(p.X + row*Dd))[tid];

    float o[4];
    o[0] = rw * xv.x + (1.f - rw) * (c0.x + c1.x);
    o[1] = rw * xv.y + (1.f - rw) * (c0.y + c1.y);
    o[2] = rw * xv.z + (1.f - rw) * (c0.z + c1.z);
    o[3] = rw * xv.w + (1.f - rw) * (c0.w + c1.w);

    float sm1 = o[0] + o[1] + o[2] + o[3];
    float sq  = o[0]*o[0] + o[1]*o[1] + o[2]*o[2] + o[3]*o[3];
    #pragma unroll
    for (int off = 32; off > 0; off >>= 1) { sm1 += __shfl_xor(sm1, off); sq += __shfl_xor(sq, off); }
    if (lane == 0) { rs[wid] = sm1; rq[wid] = sq; }
    __syncthreads();
    sm1 = rs[0] + rs[1] + rs[2] + rs[3];
    sq  = rq[0] + rq[1] + rq[2] + rq[3];
    float mu  = sm1 * (1.f/1024.f);
    float var = sq * (1.f/1024.f) - mu*mu;
    float inv = rsqrtf(var + 1e-5f);

    float4 lw = ((const float4*)p.lnw)[tid];
    float4 lb = ((const float4*)p.lnb)[tid];
    float4 y;
    y.x = (o[0] - mu)*inv*lw.x + lb.x;
    y.y = (o[1] - mu)*inv*lw.y + lb.y;
    y.z = (o[2] - mu)*inv*lw.z + lb.z;
    y.w = (o[3] - mu)*inv*lw.w + lb.w;
    ((float4*)(p.out + row*Dd))[tid] = y;
}

extern "C" void kernel_launch(void* const* d_in, const int* in_sizes, int n_in,
                              void* d_out, int out_size, void* d_ws, size_t ws_size,
                              hipStream_t stream)
{
    Params prm;
    prm.X     = (const float*)d_in[0];
    prm.posW  = (const float*)d_in[1];
    prm.posB  = (const float*)d_in[2];
    prm.pbias = (const float*)d_in[3];
    prm.spos  = (const float*)d_in[4];
    prm.lsc   = (const float*)d_in[5];
    prm.qW    = (const float*)d_in[6];
    prm.kW    = (const float*)d_in[7];
    prm.vW    = (const float*)d_in[8];
    prm.gates = (const float*)d_in[9];
    prm.rwp   = (const float*)d_in[10];
    prm.lnw   = (const float*)d_in[11];
    prm.lnb   = (const float*)d_in[12];

    char* ws = (char*)d_ws;
    size_t off = 0;
    prm.Xb  = (bf16*)(ws + off);   off += (size_t)Bb*Ss*Dd*2;
    prm.Wt  = (bf16*)(ws + off);   off += (size_t)3*Dd*Dd*2;
    prm.WpT = (bf16*)(ws + off);   off += (size_t)Ee*Dd*2;
    prm.QKV = (bf16*)(ws + off);   off += (size_t)3*Bb*Ss*Dd*2;
    prm.Vt  = (bf16*)(ws + off);   off += (size_t)Bb*Dd*Ss*2;
    prm.Aav = (bf16*)(ws + off);   off += (size_t)Bb*Ss*Ss*2;
    prm.wh  = (__half*)(ws + off); off += (size_t)Bb*Ss*Nn*2;
    prm.qk0 = (float*)(ws + off);  off += (size_t)Bb*Ss*Ss*4;
    prm.qk1 = (float*)(ws + off);  off += (size_t)Bb*Ss*Ss*4;
    prm.cb0 = (float*)(ws + off);  off += (size_t)Bb*Ss*Dd*4;
    prm.cb1 = (float*)(ws + off);  off += (size_t)Bb*Ss*Dd*4;
    prm.out = (float*)d_out;
    (void)ws_size;

    k_prep    <<<dim3(16,16,4), 256, 0, stream>>>(prm);
    k_qkv_pos <<<800,            256, 0, stream>>>(prm);
    k_qkt_vt  <<<544,            256, 0, stream>>>(prm);
    k_softmax <<<dim3(256, 2),   256, 0, stream>>>(prm);
    k_av      <<<384,            256, 0, stream>>>(prm);
    k_epilogue<<<2048,           256, 0, stream>>>(prm);
}